// Round 9
// baseline (221.130 us; speedup 1.0000x reference)
//
#include <hip/hip_runtime.h>
#include <hip/hip_bf16.h>
#include <cstddef>

typedef unsigned int uint;
typedef unsigned short ushort_t;
typedef __attribute__((ext_vector_type(8))) short bf16x8;
typedef __attribute__((ext_vector_type(4))) float f32x4;

constexpr int NB   = 2;
constexpr int NP   = 256;
constexpr int DIM  = 1024;
constexpr int NH   = 16;
constexpr int HD   = 64;
constexpr int SEQ  = 2048;
constexpr int MROW = NB * SEQ;      // 4096
constexpr int N3   = 3 * DIM;       // 3072
// softmax in base-2: fold hd^-0.5 * log2(e) into q
constexpr float QS = 0.125f * 1.4426950408889634f;

__device__ __forceinline__ ushort_t f2bf(float x) {
  uint u = __builtin_bit_cast(uint, x);
  u = (u + 0x7fff + ((u >> 16) & 1)) >> 16;   // round-to-nearest-even
  return (ushort_t)u;
}
__device__ __forceinline__ uint pack_bf16(float a, float b) {
  __hip_bfloat162 h = __float22bfloat162_rn(float2{a, b});
  uint u; __builtin_memcpy(&u, &h, 4);        // v_cvt_pk_bf16_f32
  return u;
}
__device__ __forceinline__ float bf2f(ushort_t h) {
  return __builtin_bit_cast(float, (uint)h << 16);
}

__device__ __forceinline__ void gload16(const void* g, void* l) {
  __builtin_amdgcn_global_load_lds((const __attribute__((address_space(1))) uint*)g,
                                   (__attribute__((address_space(3))) uint*)l, 16, 0, 0);
}

// ---------------- K0: RoPE cos/sin table ------------------------------------
__global__ __launch_bounds__(256) void rope_table_kernel(float* __restrict__ tab) {
  int idx = blockIdx.x * 256 + threadIdx.x;
  if (idx >= SEQ * 32) return;
  int l = idx >> 5, i = idx & 31;
  float j = (float)(i & 15);
  float invf = exp2f(-j * (13.287712379549449f / 16.f));
  float pos = (i < 16) ? (float)(l >> 8) : (float)(l & (NP - 1));
  float ang = pos * invf;
  tab[idx]            = cosf(ang);
  tab[SEQ * 32 + idx] = sinf(ang);
}

// ---------------- conversions ------------------------------------------------
__global__ __launch_bounds__(256) void cvt_bf16_kernel(
    const float* __restrict__ s, ushort_t* __restrict__ d, int n4) {
  int i = blockIdx.x * 256 + threadIdx.x;
  if (i >= n4) return;
  float4 v = reinterpret_cast<const float4*>(s)[i];
  uint2 o; o.x = pack_bf16(v.x, v.y); o.y = pack_bf16(v.z, v.w);
  reinterpret_cast<uint2*>(d)[i] = o;
}

__global__ __launch_bounds__(256) void cvt_split_kernel(
    const float* __restrict__ s, ushort_t* __restrict__ hi,
    ushort_t* __restrict__ lo, int n4) {
  int i = blockIdx.x * 256 + threadIdx.x;
  if (i >= n4) return;
  float4 v = reinterpret_cast<const float4*>(s)[i];
  float f[4] = {v.x, v.y, v.z, v.w};
  ushort_t h[4], l[4];
#pragma unroll
  for (int j = 0; j < 4; ++j) {
    h[j] = f2bf(f[j]);
    l[j] = f2bf(f[j] - bf2f(h[j]));
  }
  uint2 oh{(uint)h[0] | ((uint)h[1] << 16), (uint)h[2] | ((uint)h[3] << 16)};
  uint2 ol{(uint)l[0] | ((uint)l[1] << 16), (uint)l[2] | ((uint)l[3] << 16)};
  reinterpret_cast<uint2*>(hi)[i] = oh;
  reinterpret_cast<uint2*>(lo)[i] = ol;
}

// ---------------- bf16 MFMA GEMM: C[M][N] = A[M][K] * B[N][K]^T --------------
// 2-phase double-buffered: stage(t+1) issued BEFORE compute(t); single
// __syncthreads()/iter (its vmcnt(0) drain is exactly the wait for t+1).
template<int BM, bool SPLIT, bool BF16OUT>
__global__ __launch_bounds__(256) void gemm_mfma_kernel(
    const ushort_t* __restrict__ Ah_, const ushort_t* __restrict__ Al_,
    const ushort_t* __restrict__ Bh_, const ushort_t* __restrict__ Bl_,
    void* __restrict__ Cv, int N, int K) {
  constexpr int MF = BM / 32;               // m-frags per wave
  constexpr int REG = (BM + 128) * 128;     // bytes per (A,B) tile pair
  constexpr int PH  = (SPLIT ? 2 : 1) * REG; // bytes per phase
  __shared__ __align__(16) char smem[2 * PH];
  const int tid = threadIdx.x;
  const int l = tid & 63, w4 = tid >> 6;
  const int l7 = l & 7, l3 = l >> 3, lm = l & 15, lw = l >> 4;
  const int wm = w4 >> 1, wn = w4 & 1;
  const int bm = blockIdx.y * BM, bn = blockIdx.x * 128;
  const uint rloc = (uint)(w4 * 8 + l3);
  const uint csrc = (uint)((l7 ^ l3) << 4);
  const uint sw = (uint)(lm & 7);

  f32x4 acc[MF][4] = {};

  auto stageAB = [&](const ushort_t* A_, const ushort_t* B_, int dstoff, int k0) {
    const char* Ab = reinterpret_cast<const char*>(A_);
    const char* Bb = reinterpret_cast<const char*>(B_);
#pragma unroll
    for (int i = 0; i < BM / 32; ++i)
      gload16(Ab + (((size_t)(bm + i * 32 + rloc) * K + k0) << 1) + csrc,
              smem + dstoff + (i * 32 + w4 * 8) * 128);
#pragma unroll
    for (int i = 0; i < 4; ++i)
      gload16(Bb + (((size_t)(bn + i * 32 + rloc) * K + k0) << 1) + csrc,
              smem + dstoff + BM * 128 + (i * 32 + w4 * 8) * 128);
  };

  // prologue: stage tile 0 into phase 0
  stageAB(Ah_, Bh_, 0, 0);
  if constexpr (SPLIT) stageAB(Al_, Bl_, REG, 0);
  __syncthreads();

  int cur = 0;
  for (int k0 = 0; k0 < K; k0 += 64) {
    const int nxt = cur ^ 1;
    if (k0 + 64 < K) {
      stageAB(Ah_, Bh_, nxt * PH, k0 + 64);
      if constexpr (SPLIT) stageAB(Al_, Bl_, nxt * PH + REG, k0 + 64);
    }
    const char* As = smem + cur * PH;
    const char* Bs = As + BM * 128;
    bf16x8 af[MF][2], bfr[4][2];
#pragma unroll
    for (int mi = 0; mi < MF; ++mi)
#pragma unroll
      for (int ks = 0; ks < 2; ++ks)
        af[mi][ks] = *reinterpret_cast<const bf16x8*>(
            As + (wm * (BM / 2) + mi * 16 + lm) * 128 + ((((uint)ks * 4 + lw) ^ sw) << 4));
#pragma unroll
    for (int ni = 0; ni < 4; ++ni)
#pragma unroll
      for (int ks = 0; ks < 2; ++ks)
        bfr[ni][ks] = *reinterpret_cast<const bf16x8*>(
            Bs + (wn * 64 + ni * 16 + lm) * 128 + ((((uint)ks * 4 + lw) ^ sw) << 4));
#pragma unroll
    for (int ks = 0; ks < 2; ++ks)
#pragma unroll
      for (int mi = 0; mi < MF; ++mi)
#pragma unroll
        for (int ni = 0; ni < 4; ++ni)
          acc[mi][ni] = __builtin_amdgcn_mfma_f32_16x16x32_bf16(
              af[mi][ks], bfr[ni][ks], acc[mi][ni], 0, 0, 0);
    if constexpr (SPLIT) {
      const char* As2 = As + REG;
      const char* Bs2 = As2 + BM * 128;
      {  // al * bh   (al freed before bl loads -> lower reg pressure)
        bf16x8 al[MF][2];
#pragma unroll
        for (int mi = 0; mi < MF; ++mi)
#pragma unroll
          for (int ks = 0; ks < 2; ++ks)
            al[mi][ks] = *reinterpret_cast<const bf16x8*>(
                As2 + (wm * (BM / 2) + mi * 16 + lm) * 128 + ((((uint)ks * 4 + lw) ^ sw) << 4));
#pragma unroll
        for (int ks = 0; ks < 2; ++ks)
#pragma unroll
          for (int mi = 0; mi < MF; ++mi)
#pragma unroll
            for (int ni = 0; ni < 4; ++ni)
              acc[mi][ni] = __builtin_amdgcn_mfma_f32_16x16x32_bf16(
                  al[mi][ks], bfr[ni][ks], acc[mi][ni], 0, 0, 0);
      }
      {  // ah * bl
        bf16x8 bl[4][2];
#pragma unroll
        for (int ni = 0; ni < 4; ++ni)
#pragma unroll
          for (int ks = 0; ks < 2; ++ks)
            bl[ni][ks] = *reinterpret_cast<const bf16x8*>(
                Bs2 + (wn * 64 + ni * 16 + lm) * 128 + ((((uint)ks * 4 + lw) ^ sw) << 4));
#pragma unroll
        for (int ks = 0; ks < 2; ++ks)
#pragma unroll
          for (int mi = 0; mi < MF; ++mi)
#pragma unroll
            for (int ni = 0; ni < 4; ++ni)
              acc[mi][ni] = __builtin_amdgcn_mfma_f32_16x16x32_bf16(
                  af[mi][ks], bl[ni][ks], acc[mi][ni], 0, 0, 0);
      }
    }
    __syncthreads();   // drains vmcnt(0): next phase staged; cur readers done
    cur ^= 1;
  }
#pragma unroll
  for (int mi = 0; mi < MF; ++mi)
#pragma unroll
    for (int ni = 0; ni < 4; ++ni) {
      f32x4 a = acc[mi][ni];
      const int row0 = bm + wm * (BM / 2) + mi * 16 + lw * 4;
      const int col  = bn + wn * 64 + ni * 16 + lm;
      if constexpr (BF16OUT) {
        ushort_t* Cb = (ushort_t*)Cv;
#pragma unroll
        for (int r = 0; r < 4; ++r)
          Cb[(size_t)(row0 + r) * N + col] = f2bf(a[r]);
      } else {
        float* Cf = (float*)Cv;
#pragma unroll
        for (int r = 0; r < 4; ++r)
          Cf[(size_t)(row0 + r) * N + col] = a[r];
      }
    }
}

// ---------------- K2: RMSNorm + RoPE (bf16 in); qT/kT row-major, vT d-major --
__global__ __launch_bounds__(256) void qkv_post_kernel(
    const ushort_t* __restrict__ qkv, const float* __restrict__ qs,
    const float* __restrict__ ksc, const float* __restrict__ tab,
    ushort_t* __restrict__ qT, ushort_t* __restrict__ kT, ushort_t* __restrict__ vT) {
  __shared__ ushort_t vt[64][72];
  const int bx = blockIdx.x;
  const int h = bx & 15, lt = (bx >> 4) & 31, b = bx >> 9;
  const int t = threadIdx.x, lr = t >> 2, s = t & 3, d0 = s * 16;
  const int lg = lt * 64 + lr;
  const int bh = b * NH + h;
  const ushort_t* rowp = qkv + ((size_t)(b * SEQ + lg) * N3) + h * HD + d0;

  ushort_t qraw[16], kraw[16], vraw[16];
  *reinterpret_cast<uint4*>(&qraw[0]) = *reinterpret_cast<const uint4*>(rowp);
  *reinterpret_cast<uint4*>(&qraw[8]) = *reinterpret_cast<const uint4*>(rowp + 8);
  *reinterpret_cast<uint4*>(&kraw[0]) = *reinterpret_cast<const uint4*>(rowp + DIM);
  *reinterpret_cast<uint4*>(&kraw[8]) = *reinterpret_cast<const uint4*>(rowp + DIM + 8);
  *reinterpret_cast<uint4*>(&vraw[0]) = *reinterpret_cast<const uint4*>(rowp + 2 * DIM);
  *reinterpret_cast<uint4*>(&vraw[8]) = *reinterpret_cast<const uint4*>(rowp + 2 * DIM + 8);
  float4 qs4[4], ks4[4];
#pragma unroll
  for (int u = 0; u < 4; ++u) {
    qs4[u] = *reinterpret_cast<const float4*>(qs + d0 + u * 4);
    ks4[u] = *reinterpret_cast<const float4*>(ksc + d0 + u * 4);
  }
  const float* sq_ = reinterpret_cast<const float*>(qs4);
  const float* sk_ = reinterpret_cast<const float*>(ks4);
  float vq[16], vk[16];
#pragma unroll
  for (int j = 0; j < 16; ++j) { vq[j] = bf2f(qraw[j]); vk[j] = bf2f(kraw[j]); }

  float sq = 0.f, sk = 0.f;
#pragma unroll
  for (int j = 0; j < 16; ++j) { sq = fmaf(vq[j], vq[j], sq); sk = fmaf(vk[j], vk[j], sk); }
  sq += __shfl_xor(sq, 1); sq += __shfl_xor(sq, 2);
  sk += __shfl_xor(sk, 1); sk += __shfl_xor(sk, 2);
  float rq = rsqrtf(sq * (1.f / HD) + 1e-6f);
  float rk = rsqrtf(sk * (1.f / HD) + 1e-6f);

  float4 c4[2], s4[2];
  const float* tc = tab + (size_t)lg * 32 + s * 8;
  const float* ts = tab + (size_t)SEQ * 32 + (size_t)lg * 32 + s * 8;
  c4[0] = *reinterpret_cast<const float4*>(tc);
  c4[1] = *reinterpret_cast<const float4*>(tc + 4);
  s4[0] = *reinterpret_cast<const float4*>(ts);
  s4[1] = *reinterpret_cast<const float4*>(ts + 4);
  const float* cj = reinterpret_cast<const float*>(c4);
  const float* sj = reinterpret_cast<const float*>(s4);

  uint uq[8], uk[8], uv[8];
#pragma unroll
  for (int j = 0; j < 8; ++j) {
    float qe = vq[2*j] * rq * sq_[2*j], qo = vq[2*j+1] * rq * sq_[2*j+1];
    float ke = vk[2*j] * rk * sk_[2*j], ko = vk[2*j+1] * rk * sk_[2*j+1];
    float c = cj[j], sn = sj[j];
    uq[j] = pack_bf16((qe * c - qo * sn) * QS, (qe * sn + qo * c) * QS);
    uk[j] = pack_bf16(ke * c - ko * sn, ke * sn + ko * c);
    uv[j] = (uint)vraw[2*j] | ((uint)vraw[2*j+1] << 16);
  }
  ushort_t* qp = qT + ((size_t)bh * SEQ + lg) * HD + d0;
  ushort_t* kp = kT + ((size_t)bh * SEQ + lg) * HD + d0;
  reinterpret_cast<uint4*>(qp)[0] = *reinterpret_cast<uint4*>(&uq[0]);
  reinterpret_cast<uint4*>(qp)[1] = *reinterpret_cast<uint4*>(&uq[4]);
  reinterpret_cast<uint4*>(kp)[0] = *reinterpret_cast<uint4*>(&uk[0]);
  reinterpret_cast<uint4*>(kp)[1] = *reinterpret_cast<uint4*>(&uk[4]);
#pragma unroll
  for (int j = 0; j < 16; ++j)
    vt[d0 + j][lr] = (ushort_t)((j & 1) ? (uv[j >> 1] >> 16) : (uv[j >> 1] & 0xffff));
  __syncthreads();
  const int drow = t >> 2, lc = (t & 3) * 16;
  ushort_t* vp = vT + ((size_t)bh * HD + drow) * SEQ + lt * 64 + lc;
  reinterpret_cast<uint4*>(vp)[0] = *reinterpret_cast<const uint4*>(&vt[drow][lc]);
  reinterpret_cast<uint4*>(vp)[1] = *reinterpret_cast<const uint4*>(&vt[drow][lc + 8]);
}

// ---------------- K3: bf16 MFMA block-causal flash attention -----------------
// 8 waves: group0 (waves 0-3) even k-tiles, group1 (waves 4-7) odd k-tiles.
// K/V fragments loaded DIRECTLY global->register (read-once data; LDS staging
// added no reuse). Software-pipelined 2-set register prefetch; NO barriers in
// the main loop -> waves drift freely, 2 waves/SIMD self-interleave stalls.
// P round-trip stays in wave-private LDS. Pair-balanced (15-p, p): iters even.
__global__ __launch_bounds__(512) void attn_mfma_kernel(
    const ushort_t* __restrict__ qT, const ushort_t* __restrict__ kT,
    const ushort_t* __restrict__ vT, ushort_t* __restrict__ ahi,
    ushort_t* __restrict__ alo) {
  __shared__ __align__(16) char smem[69632];  // loop: P 8x4K; epilogue: merge 68K
  const int tid = threadIdx.x;
  const int l  = tid & 63, w8 = tid >> 6;
  const int grp = w8 >> 2, w4 = w8 & 3;
  const int lm = l & 15, lw = l >> 4, l7 = l & 7;
  const int bh = blockIdx.y, b = bh >> 4, h = bh & 15;
  const int p = blockIdx.x;
  const int qbA = 15 - p, qbB = p;
  const int nkbA = ((qbA >> 1) + 1) * 4;       // 20..32
  const int nkbB = ((qbB >> 1) + 1) * 4;       // 4..16 (prefix of A's range)
  const int iters  = nkbA >> 1;                // 10..16, always EVEN
  const int bIters = nkbB >> 1;

  bf16x8 qf[2][2][2];                          // [tile][qm][ks]
#pragma unroll
  for (int tq = 0; tq < 2; ++tq) {
    const size_t qrow0 = (size_t)bh * SEQ + (tq ? qbB : qbA) * 128 + w4 * 32;
#pragma unroll
    for (int qm = 0; qm < 2; ++qm)
#pragma unroll
      for (int ks = 0; ks < 2; ++ks)
        qf[tq][qm][ks] = *reinterpret_cast<const bf16x8*>(
            qT + (qrow0 + qm * 16 + lm) * HD + lw * 8 + ks * 32);
  }

  const char* kTb = reinterpret_cast<const char*>(kT + (size_t)bh * SEQ * HD);
  const char* vTb = reinterpret_cast<const char*>(vT + (size_t)bh * HD * SEQ);
  char* Pbase = smem + w8 * 4096;

  float l_acc[2][2] = {};
  f32x4 oacc[2][2][4] = {};

  // direct global->register fragment loads (same lane mapping as staged path)
  auto loadKV = [&](int kb, bf16x8 (&kf)[2][4], bf16x8 (&vf)[2][4]) {
#pragma unroll
    for (int ks = 0; ks < 2; ++ks)
#pragma unroll
      for (int g = 0; g < 4; ++g)
        kf[ks][g] = *reinterpret_cast<const bf16x8*>(
            kTb + (size_t)(kb * 64 + g * 16 + lm) * 128 + lw * 16 + ks * 64);
#pragma unroll
    for (int ks = 0; ks < 2; ++ks)
#pragma unroll
      for (int dn = 0; dn < 4; ++dn)
        vf[ks][dn] = *reinterpret_cast<const bf16x8*>(
            vTb + (size_t)(dn * 16 + lm) * (SEQ * 2) + (size_t)kb * 128 + lw * 16 + ks * 64);
  };

  auto qkt = [&](const bf16x8 (&kf)[2][4], const bf16x8 (&qft)[2][2],
                 f32x4 (&st)[2][4]) {
    __builtin_amdgcn_s_setprio(1);
#pragma unroll
    for (int ks = 0; ks < 2; ++ks)
#pragma unroll
      for (int g = 0; g < 4; ++g) {
        st[0][g] = __builtin_amdgcn_mfma_f32_16x16x32_bf16(kf[ks][g], qft[0][ks], st[0][g], 0, 0, 0);
        st[1][g] = __builtin_amdgcn_mfma_f32_16x16x32_bf16(kf[ks][g], qft[1][ks], st[1][g], 0, 0, 0);
      }
    __builtin_amdgcn_s_setprio(0);
  };

  auto sm_pv = [&](f32x4 (&st)[2][4], float (&lat)[2], f32x4 (&oat)[2][4],
                   const bf16x8 (&vf)[2][4]) {
#pragma unroll
    for (int qm = 0; qm < 2; ++qm)
#pragma unroll
      for (int g = 0; g < 4; ++g) {
        f32x4 s4 = st[qm][g];
        float p0 = __builtin_amdgcn_exp2f(s4.x);
        float p1 = __builtin_amdgcn_exp2f(s4.y);
        float p2 = __builtin_amdgcn_exp2f(s4.z);
        float p3 = __builtin_amdgcn_exp2f(s4.w);
        lat[qm] += (p0 + p1) + (p2 + p3);
        uint off = (uint)((qm * 16 + lm) * 128 + ((g * 32 + lw * 8) ^ (l7 << 4)));
        *reinterpret_cast<uint*>(Pbase + off)     = pack_bf16(p0, p1);
        *reinterpret_cast<uint*>(Pbase + off + 4) = pack_bf16(p2, p3);
      }
    bf16x8 pf[2][2];
#pragma unroll
    for (int qm = 0; qm < 2; ++qm)
#pragma unroll
      for (int ks = 0; ks < 2; ++ks)
        pf[qm][ks] = *reinterpret_cast<const bf16x8*>(
            Pbase + (qm * 16 + lm) * 128 + ((lw * 16 + ks * 64) ^ (l7 << 4)));
    __builtin_amdgcn_s_setprio(1);
#pragma unroll
    for (int ks = 0; ks < 2; ++ks)
#pragma unroll
      for (int dn = 0; dn < 4; ++dn) {
        oat[0][dn] = __builtin_amdgcn_mfma_f32_16x16x32_bf16(vf[ks][dn], pf[0][ks], oat[0][dn], 0, 0, 0);
        oat[1][dn] = __builtin_amdgcn_mfma_f32_16x16x32_bf16(vf[ks][dn], pf[1][ks], oat[1][dn], 0, 0, 0);
      }
    __builtin_amdgcn_s_setprio(0);
  };

  auto iterAB = [&](int i, const bf16x8 (&kf)[2][4], const bf16x8 (&vf)[2][4]) {
    f32x4 stA[2][4] = {};
    qkt(kf, qf[0], stA);
    sm_pv(stA, l_acc[0], oacc[0], vf);
    if (i < bIters) {
      f32x4 stB[2][4] = {};
      qkt(kf, qf[1], stB);
      sm_pv(stB, l_acc[1], oacc[1], vf);
    }
  };

  // software pipeline: two named register sets, unroll-2 (iters is even)
  bf16x8 kfA[2][4], vfA[2][4], kfB[2][4], vfB[2][4];
  loadKV(grp, kfA, vfA);
  for (int i = 0; i < iters; i += 2) {
    loadKV(2 * (i + 1) + grp, kfB, vfB);     // prefetch while computing A
    iterAB(i, kfA, vfA);
    if (i + 2 < iters) loadKV(2 * (i + 2) + grp, kfA, vfA);
    iterAB(i + 1, kfB, vfB);
  }

  // merge group partials: group1 -> LDS, group0 adds (slot-major, 16B/lane).
  __syncthreads();
  if (grp == 1) {
#pragma unroll
    for (int tq = 0; tq < 2; ++tq)
#pragma unroll
      for (int qm = 0; qm < 2; ++qm)
#pragma unroll
        for (int dn = 0; dn < 4; ++dn)
          *reinterpret_cast<f32x4*>(
              smem + ((tq * 2 + qm) * 4 + dn) * 4096 + (w4 * 64 + l) * 16) = oacc[tq][qm][dn];
    float4 lv{l_acc[0][0], l_acc[0][1], l_acc[1][0], l_acc[1][1]};
    *reinterpret_cast<float4*>(smem + 65536 + (w4 * 64 + l) * 16) = lv;
  }
  __syncthreads();
  if (grp == 0) {
#pragma unroll
    for (int tq = 0; tq < 2; ++tq)
#pragma unroll
      for (int qm = 0; qm < 2; ++qm)
#pragma unroll
        for (int dn = 0; dn < 4; ++dn)
          oacc[tq][qm][dn] += *reinterpret_cast<const f32x4*>(
              smem + ((tq * 2 + qm) * 4 + dn) * 4096 + (w4 * 64 + l) * 16);
    float4 lv = *reinterpret_cast<const float4*>(smem + 65536 + (w4 * 64 + l) * 16);
    l_acc[0][0] += lv.x; l_acc[0][1] += lv.y; l_acc[1][0] += lv.z; l_acc[1][1] += lv.w;

#pragma unroll
    for (int tq = 0; tq < 2; ++tq) {
      const int qb = tq ? qbB : qbA;
#pragma unroll
      for (int qm = 0; qm < 2; ++qm) {
        float ls = (tq ? l_acc[1] : l_acc[0])[qm];
        ls += __shfl_xor(ls, 16);
        ls += __shfl_xor(ls, 32);
        float inv = 1.f / ls;
        const int qg = qb * 128 + w4 * 32 + qm * 16 + lm;
#pragma unroll
        for (int dn = 0; dn < 4; ++dn) {
          f32x4 o = (tq ? oacc[1] : oacc[0])[qm][dn];
          o *= inv;
          ushort_t hh[4], ll[4];
#pragma unroll
          for (int j = 0; j < 4; ++j) {
            hh[j] = f2bf(o[j]);
            ll[j] = f2bf(o[j] - bf2f(hh[j]));
          }
          size_t off = ((size_t)b * SEQ + qg) * DIM + h * HD + dn * 16 + lw * 4;
          uint2 uh{(uint)hh[0] | ((uint)hh[1] << 16), (uint)hh[2] | ((uint)hh[3] << 16)};
          uint2 ul{(uint)ll[0] | ((uint)ll[1] << 16), (uint)ll[2] | ((uint)ll[3] << 16)};
          *reinterpret_cast<uint2*>(&ahi[off]) = uh;
          *reinterpret_cast<uint2*>(&alo[off]) = ul;
        }
      }
    }
  }
}

// ---------------- launch -----------------------------------------------------
extern "C" void kernel_launch(void* const* d_in, const int* in_sizes, int n_in,
                              void* d_out, int out_size, void* d_ws, size_t ws_size,
                              hipStream_t stream) {
  const float* x       = (const float*)d_in[0];
  const float* Wqkv    = (const float*)d_in[1];
  const float* Wout    = (const float*)d_in[2];
  const float* q_scale = (const float*)d_in[3];
  const float* k_scale = (const float*)d_in[4];
  float* out = (float*)d_out;

  char* ws = (char*)d_ws;
  ushort_t* qkv = (ushort_t*)ws;                           // 25.2 MB bf16
  ushort_t* attn_hi = (ushort_t*)ws;                       // reuse qkv region
  ushort_t* attn_lo = attn_hi + (size_t)MROW * DIM;
  size_t off = (size_t)MROW * N3 * 2;
  ushort_t* qT = (ushort_t*)(ws + off); off += (size_t)NB * NH * SEQ * HD * 2;
  ushort_t* kT = (ushort_t*)(ws + off); off += (size_t)NB * NH * SEQ * HD * 2;
  ushort_t* vT = (ushort_t*)(ws + off); off += (size_t)NB * NH * SEQ * HD * 2;
  float* tab   = (float*)(ws + off);    off += (size_t)SEQ * 64 * 4;
  ushort_t* xh  = (ushort_t*)(ws + off); off += (size_t)MROW * DIM * 2;
  ushort_t* wqh = (ushort_t*)(ws + off); off += (size_t)N3 * DIM * 2;
  ushort_t* woh = (ushort_t*)(ws + off); off += (size_t)DIM * DIM * 2;
  ushort_t* wol = (ushort_t*)(ws + off);

  rope_table_kernel<<<dim3(SEQ * 32 / 256), dim3(256), 0, stream>>>(tab);
  cvt_bf16_kernel<<<dim3(MROW * DIM / 4 / 256), dim3(256), 0, stream>>>(x, xh, MROW * DIM / 4);
  cvt_bf16_kernel<<<dim3(N3 * DIM / 4 / 256), dim3(256), 0, stream>>>(Wqkv, wqh, N3 * DIM / 4);
  cvt_split_kernel<<<dim3(DIM * DIM / 4 / 256), dim3(256), 0, stream>>>(Wout, woh, wol, DIM * DIM / 4);
  gemm_mfma_kernel<128, false, true><<<dim3(N3 / 128, MROW / 128), dim3(256), 0, stream>>>(
      xh, nullptr, wqh, nullptr, qkv, N3, DIM);
  qkv_post_kernel<<<dim3(NB * 32 * NH), dim3(256), 0, stream>>>(qkv, q_scale, k_scale, tab, qT, kT, vT);
  attn_mfma_kernel<<<dim3(8, NB * NH), dim3(512), 0, stream>>>(qT, kT, vT, attn_hi, attn_lo);
  gemm_mfma_kernel<128, true, false><<<dim3(DIM / 128, MROW / 128), dim3(256), 0, stream>>>(
      attn_hi, attn_lo, woh, wol, out, DIM, DIM);
}

// Round 10
// 117.898 us; speedup vs baseline: 1.8756x; 1.8756x over previous
//
#include <hip/hip_runtime.h>
#include <hip/hip_bf16.h>
#include <cstddef>

typedef unsigned int uint;
typedef unsigned short ushort_t;
typedef __attribute__((ext_vector_type(8))) short bf16x8;
typedef __attribute__((ext_vector_type(8))) _Float16 f16x8;
typedef __attribute__((ext_vector_type(4))) float f32x4;

constexpr int NB   = 2;
constexpr int NP   = 256;
constexpr int DIM  = 1024;
constexpr int NH   = 16;
constexpr int HD   = 64;
constexpr int SEQ  = 2048;
constexpr int MROW = NB * SEQ;      // 4096
constexpr int N3   = 3 * DIM;       // 3072
// softmax in base-2: fold hd^-0.5 * log2(e) into q
constexpr float QS = 0.125f * 1.4426950408889634f;

__device__ __forceinline__ ushort_t f2bf(float x) {
  uint u = __builtin_bit_cast(uint, x);
  u = (u + 0x7fff + ((u >> 16) & 1)) >> 16;   // round-to-nearest-even
  return (ushort_t)u;
}
__device__ __forceinline__ uint pack_bf16(float a, float b) {
  __hip_bfloat162 h = __float22bfloat162_rn(float2{a, b});
  uint u; __builtin_memcpy(&u, &h, 4);        // v_cvt_pk_bf16_f32
  return u;
}
__device__ __forceinline__ float bf2f(ushort_t h) {
  return __builtin_bit_cast(float, (uint)h << 16);
}
__device__ __forceinline__ ushort_t f2h(float x) {
  _Float16 h = (_Float16)x;
  ushort_t u; __builtin_memcpy(&u, &h, 2);
  return u;
}

template<bool F16>
__device__ __forceinline__ f32x4 mfma16(bf16x8 a, bf16x8 b, f32x4 c) {
  if constexpr (F16) {
    f16x8 af = __builtin_bit_cast(f16x8, a);
    f16x8 bf = __builtin_bit_cast(f16x8, b);
    return __builtin_amdgcn_mfma_f32_16x16x32_f16(af, bf, c, 0, 0, 0);
  } else {
    return __builtin_amdgcn_mfma_f32_16x16x32_bf16(a, b, c, 0, 0, 0);
  }
}

__device__ __forceinline__ void gload16(const void* g, void* l) {
  __builtin_amdgcn_global_load_lds((const __attribute__((address_space(1))) uint*)g,
                                   (__attribute__((address_space(3))) uint*)l, 16, 0, 0);
}

// ---------------- K0: RoPE cos/sin table ------------------------------------
__global__ __launch_bounds__(256) void rope_table_kernel(float* __restrict__ tab) {
  int idx = blockIdx.x * 256 + threadIdx.x;
  if (idx >= SEQ * 32) return;
  int l = idx >> 5, i = idx & 31;
  float j = (float)(i & 15);
  float invf = exp2f(-j * (13.287712379549449f / 16.f));
  float pos = (i < 16) ? (float)(l >> 8) : (float)(l & (NP - 1));
  float ang = pos * invf;
  tab[idx]            = cosf(ang);
  tab[SEQ * 32 + idx] = sinf(ang);
}

// ---------------- conversions ------------------------------------------------
__global__ __launch_bounds__(256) void cvt_bf16_kernel(
    const float* __restrict__ s, ushort_t* __restrict__ d, int n4) {
  int i = blockIdx.x * 256 + threadIdx.x;
  if (i >= n4) return;
  float4 v = reinterpret_cast<const float4*>(s)[i];
  uint2 o; o.x = pack_bf16(v.x, v.y); o.y = pack_bf16(v.z, v.w);
  reinterpret_cast<uint2*>(d)[i] = o;
}

__global__ __launch_bounds__(256) void cvt_f16_kernel(
    const float* __restrict__ s, ushort_t* __restrict__ d, int n4) {
  int i = blockIdx.x * 256 + threadIdx.x;
  if (i >= n4) return;
  float4 v = reinterpret_cast<const float4*>(s)[i];
  uint2 o;
  o.x = (uint)f2h(v.x) | ((uint)f2h(v.y) << 16);
  o.y = (uint)f2h(v.z) | ((uint)f2h(v.w) << 16);
  reinterpret_cast<uint2*>(d)[i] = o;
}

// ---------------- 16-bit MFMA GEMM: C[M][N] = A[M][K] * B[N][K]^T ------------
// 2-phase double-buffered: stage(t+1) issued BEFORE compute(t); single
// __syncthreads()/iter (its vmcnt(0) drain is exactly the wait for t+1).
template<int BM, bool SPLIT, bool BF16OUT, bool F16>
__global__ __launch_bounds__(256) void gemm_mfma_kernel(
    const ushort_t* __restrict__ Ah_, const ushort_t* __restrict__ Al_,
    const ushort_t* __restrict__ Bh_, const ushort_t* __restrict__ Bl_,
    void* __restrict__ Cv, int N, int K) {
  constexpr int MF = BM / 32;               // m-frags per wave
  constexpr int REG = (BM + 128) * 128;     // bytes per (A,B) tile pair
  constexpr int PH  = (SPLIT ? 2 : 1) * REG; // bytes per phase
  __shared__ __align__(16) char smem[2 * PH];
  const int tid = threadIdx.x;
  const int l = tid & 63, w4 = tid >> 6;
  const int l7 = l & 7, l3 = l >> 3, lm = l & 15, lw = l >> 4;
  const int wm = w4 >> 1, wn = w4 & 1;
  const int bm = blockIdx.y * BM, bn = blockIdx.x * 128;
  const uint rloc = (uint)(w4 * 8 + l3);
  const uint csrc = (uint)((l7 ^ l3) << 4);
  const uint sw = (uint)(lm & 7);

  f32x4 acc[MF][4] = {};

  auto stageAB = [&](const ushort_t* A_, const ushort_t* B_, int dstoff, int k0) {
    const char* Ab = reinterpret_cast<const char*>(A_);
    const char* Bb = reinterpret_cast<const char*>(B_);
#pragma unroll
    for (int i = 0; i < BM / 32; ++i)
      gload16(Ab + (((size_t)(bm + i * 32 + rloc) * K + k0) << 1) + csrc,
              smem + dstoff + (i * 32 + w4 * 8) * 128);
#pragma unroll
    for (int i = 0; i < 4; ++i)
      gload16(Bb + (((size_t)(bn + i * 32 + rloc) * K + k0) << 1) + csrc,
              smem + dstoff + BM * 128 + (i * 32 + w4 * 8) * 128);
  };

  // prologue: stage tile 0 into phase 0
  stageAB(Ah_, Bh_, 0, 0);
  if constexpr (SPLIT) stageAB(Al_, Bl_, REG, 0);
  __syncthreads();

  int cur = 0;
  for (int k0 = 0; k0 < K; k0 += 64) {
    const int nxt = cur ^ 1;
    if (k0 + 64 < K) {
      stageAB(Ah_, Bh_, nxt * PH, k0 + 64);
      if constexpr (SPLIT) stageAB(Al_, Bl_, nxt * PH + REG, k0 + 64);
    }
    const char* As = smem + cur * PH;
    const char* Bs = As + BM * 128;
    bf16x8 af[MF][2], bfr[4][2];
#pragma unroll
    for (int mi = 0; mi < MF; ++mi)
#pragma unroll
      for (int ks = 0; ks < 2; ++ks)
        af[mi][ks] = *reinterpret_cast<const bf16x8*>(
            As + (wm * (BM / 2) + mi * 16 + lm) * 128 + ((((uint)ks * 4 + lw) ^ sw) << 4));
#pragma unroll
    for (int ni = 0; ni < 4; ++ni)
#pragma unroll
      for (int ks = 0; ks < 2; ++ks)
        bfr[ni][ks] = *reinterpret_cast<const bf16x8*>(
            Bs + (wn * 64 + ni * 16 + lm) * 128 + ((((uint)ks * 4 + lw) ^ sw) << 4));
#pragma unroll
    for (int ks = 0; ks < 2; ++ks)
#pragma unroll
      for (int mi = 0; mi < MF; ++mi)
#pragma unroll
        for (int ni = 0; ni < 4; ++ni)
          acc[mi][ni] = mfma16<F16>(af[mi][ks], bfr[ni][ks], acc[mi][ni]);
    if constexpr (SPLIT) {
      const char* As2 = As + REG;
      const char* Bs2 = As2 + BM * 128;
      {  // al * bh
        bf16x8 al[MF][2];
#pragma unroll
        for (int mi = 0; mi < MF; ++mi)
#pragma unroll
          for (int ks = 0; ks < 2; ++ks)
            al[mi][ks] = *reinterpret_cast<const bf16x8*>(
                As2 + (wm * (BM / 2) + mi * 16 + lm) * 128 + ((((uint)ks * 4 + lw) ^ sw) << 4));
#pragma unroll
        for (int ks = 0; ks < 2; ++ks)
#pragma unroll
          for (int mi = 0; mi < MF; ++mi)
#pragma unroll
            for (int ni = 0; ni < 4; ++ni)
              acc[mi][ni] = mfma16<F16>(al[mi][ks], bfr[ni][ks], acc[mi][ni]);
      }
      {  // ah * bl
        bf16x8 bl[4][2];
#pragma unroll
        for (int ni = 0; ni < 4; ++ni)
#pragma unroll
          for (int ks = 0; ks < 2; ++ks)
            bl[ni][ks] = *reinterpret_cast<const bf16x8*>(
                Bs2 + (wn * 64 + ni * 16 + lm) * 128 + ((((uint)ks * 4 + lw) ^ sw) << 4));
#pragma unroll
        for (int ks = 0; ks < 2; ++ks)
#pragma unroll
          for (int mi = 0; mi < MF; ++mi)
#pragma unroll
            for (int ni = 0; ni < 4; ++ni)
              acc[mi][ni] = mfma16<F16>(af[mi][ks], bl[ni][ks], acc[mi][ni]);
      }
    }
    __syncthreads();   // drains vmcnt(0): next phase staged; cur readers done
    cur ^= 1;
  }
#pragma unroll
  for (int mi = 0; mi < MF; ++mi)
#pragma unroll
    for (int ni = 0; ni < 4; ++ni) {
      f32x4 a = acc[mi][ni];
      const int row0 = bm + wm * (BM / 2) + mi * 16 + lw * 4;
      const int col  = bn + wn * 64 + ni * 16 + lm;
      if constexpr (BF16OUT) {
        ushort_t* Cb = (ushort_t*)Cv;
#pragma unroll
        for (int r = 0; r < 4; ++r)
          Cb[(size_t)(row0 + r) * N + col] = f2bf(a[r]);
      } else {
        float* Cf = (float*)Cv;
#pragma unroll
        for (int r = 0; r < 4; ++r)
          Cf[(size_t)(row0 + r) * N + col] = a[r];
      }
    }
}

// ---------------- K2: RMSNorm + RoPE (bf16 in); qT/kT row-major, vT d-major --
__global__ __launch_bounds__(256) void qkv_post_kernel(
    const ushort_t* __restrict__ qkv, const float* __restrict__ qs,
    const float* __restrict__ ksc, const float* __restrict__ tab,
    ushort_t* __restrict__ qT, ushort_t* __restrict__ kT, ushort_t* __restrict__ vT) {
  __shared__ ushort_t vt[64][72];
  const int bx = blockIdx.x;
  const int h = bx & 15, lt = (bx >> 4) & 31, b = bx >> 9;
  const int t = threadIdx.x, lr = t >> 2, s = t & 3, d0 = s * 16;
  const int lg = lt * 64 + lr;
  const int bh = b * NH + h;
  const ushort_t* rowp = qkv + ((size_t)(b * SEQ + lg) * N3) + h * HD + d0;

  ushort_t qraw[16], kraw[16], vraw[16];
  *reinterpret_cast<uint4*>(&qraw[0]) = *reinterpret_cast<const uint4*>(rowp);
  *reinterpret_cast<uint4*>(&qraw[8]) = *reinterpret_cast<const uint4*>(rowp + 8);
  *reinterpret_cast<uint4*>(&kraw[0]) = *reinterpret_cast<const uint4*>(rowp + DIM);
  *reinterpret_cast<uint4*>(&kraw[8]) = *reinterpret_cast<const uint4*>(rowp + DIM + 8);
  *reinterpret_cast<uint4*>(&vraw[0]) = *reinterpret_cast<const uint4*>(rowp + 2 * DIM);
  *reinterpret_cast<uint4*>(&vraw[8]) = *reinterpret_cast<const uint4*>(rowp + 2 * DIM + 8);
  float4 qs4[4], ks4[4];
#pragma unroll
  for (int u = 0; u < 4; ++u) {
    qs4[u] = *reinterpret_cast<const float4*>(qs + d0 + u * 4);
    ks4[u] = *reinterpret_cast<const float4*>(ksc + d0 + u * 4);
  }
  const float* sq_ = reinterpret_cast<const float*>(qs4);
  const float* sk_ = reinterpret_cast<const float*>(ks4);
  float vq[16], vk[16];
#pragma unroll
  for (int j = 0; j < 16; ++j) { vq[j] = bf2f(qraw[j]); vk[j] = bf2f(kraw[j]); }

  float sq = 0.f, sk = 0.f;
#pragma unroll
  for (int j = 0; j < 16; ++j) { sq = fmaf(vq[j], vq[j], sq); sk = fmaf(vk[j], vk[j], sk); }
  sq += __shfl_xor(sq, 1); sq += __shfl_xor(sq, 2);
  sk += __shfl_xor(sk, 1); sk += __shfl_xor(sk, 2);
  float rq = rsqrtf(sq * (1.f / HD) + 1e-6f);
  float rk = rsqrtf(sk * (1.f / HD) + 1e-6f);

  float4 c4[2], s4[2];
  const float* tc = tab + (size_t)lg * 32 + s * 8;
  const float* ts = tab + (size_t)SEQ * 32 + (size_t)lg * 32 + s * 8;
  c4[0] = *reinterpret_cast<const float4*>(tc);
  c4[1] = *reinterpret_cast<const float4*>(tc + 4);
  s4[0] = *reinterpret_cast<const float4*>(ts);
  s4[1] = *reinterpret_cast<const float4*>(ts + 4);
  const float* cj = reinterpret_cast<const float*>(c4);
  const float* sj = reinterpret_cast<const float*>(s4);

  uint uq[8], uk[8], uv[8];
#pragma unroll
  for (int j = 0; j < 8; ++j) {
    float qe = vq[2*j] * rq * sq_[2*j], qo = vq[2*j+1] * rq * sq_[2*j+1];
    float ke = vk[2*j] * rk * sk_[2*j], ko = vk[2*j+1] * rk * sk_[2*j+1];
    float c = cj[j], sn = sj[j];
    uq[j] = pack_bf16((qe * c - qo * sn) * QS, (qe * sn + qo * c) * QS);
    uk[j] = pack_bf16(ke * c - ko * sn, ke * sn + ko * c);
    uv[j] = (uint)vraw[2*j] | ((uint)vraw[2*j+1] << 16);
  }
  ushort_t* qp = qT + ((size_t)bh * SEQ + lg) * HD + d0;
  ushort_t* kp = kT + ((size_t)bh * SEQ + lg) * HD + d0;
  reinterpret_cast<uint4*>(qp)[0] = *reinterpret_cast<uint4*>(&uq[0]);
  reinterpret_cast<uint4*>(qp)[1] = *reinterpret_cast<uint4*>(&uq[4]);
  reinterpret_cast<uint4*>(kp)[0] = *reinterpret_cast<uint4*>(&uk[0]);
  reinterpret_cast<uint4*>(kp)[1] = *reinterpret_cast<uint4*>(&uk[4]);
#pragma unroll
  for (int j = 0; j < 16; ++j)
    vt[d0 + j][lr] = (ushort_t)((j & 1) ? (uv[j >> 1] >> 16) : (uv[j >> 1] & 0xffff));
  __syncthreads();
  const int drow = t >> 2, lc = (t & 3) * 16;
  ushort_t* vp = vT + ((size_t)bh * HD + drow) * SEQ + lt * 64 + lc;
  reinterpret_cast<uint4*>(vp)[0] = *reinterpret_cast<const uint4*>(&vt[drow][lc]);
  reinterpret_cast<uint4*>(vp)[1] = *reinterpret_cast<const uint4*>(&vt[drow][lc + 8]);
}

// ---------------- K3: bf16 MFMA block-causal flash attention -----------------
// R8-proven structure: 8 waves, k-split groups, 3-buffer counted-vmcnt staged
// pipeline, kf/vf hoisted once/iter, wave-private P, conflict-free merge.
// Epilogue now emits SINGLE fp16 output (feeds fp16 out-projection GEMM).
__global__ __launch_bounds__(512) void attn_mfma_kernel(
    const ushort_t* __restrict__ qT, const ushort_t* __restrict__ kT,
    const ushort_t* __restrict__ vT, ushort_t* __restrict__ aout) {
  __shared__ __align__(16) char smem[131072];
  const int tid = threadIdx.x;
  const int l  = tid & 63, w8 = tid >> 6;
  const int grp = w8 >> 2, w4 = w8 & 3;
  const int lm = l & 15, lw = l >> 4, l7 = l & 7, l3 = l >> 3;
  const int bh = blockIdx.y, b = bh >> 4, h = bh & 15;
  const int p = blockIdx.x;
  const int qbA = 15 - p, qbB = p;
  const int nkbA = ((qbA >> 1) + 1) * 4;       // 20..32 (even)
  const int nkbB = ((qbB >> 1) + 1) * 4;       // 4..16  (prefix of A's range)
  const int iters  = nkbA >> 1;
  const int bIters = nkbB >> 1;

  bf16x8 qf[2][2][2];                          // [tile][qm][ks]
#pragma unroll
  for (int tq = 0; tq < 2; ++tq) {
    const size_t qrow0 = (size_t)bh * SEQ + (tq ? qbB : qbA) * 128 + w4 * 32;
#pragma unroll
    for (int qm = 0; qm < 2; ++qm)
#pragma unroll
      for (int ks = 0; ks < 2; ++ks)
        qf[tq][qm][ks] = *reinterpret_cast<const bf16x8*>(
            qT + (qrow0 + qm * 16 + lm) * HD + lw * 8 + ks * 32);
  }

  const char* kTb = reinterpret_cast<const char*>(kT + (size_t)bh * SEQ * HD);
  const char* vTb = reinterpret_cast<const char*>(vT + (size_t)bh * HD * SEQ);
  const uint rloc = w8 >= 4 ? (w4 * 8 + l3) : (w4 * 8 + l3);
  const uint csrc = (uint)((l7 ^ l3) << 4);
  char* Pbase = smem + 98304 + w8 * 4096;

  float l_acc[2][2] = {};
  f32x4 oacc[2][2][4] = {};

  auto stage = [&](int kb, int bufidx) {
    const char* sK = kTb + ((size_t)(kb * 64) + rloc) * 128 + csrc;
    const char* sV = vTb + (size_t)rloc * (SEQ * 2) + (size_t)kb * 128 + csrc;
    char* dK = smem + (grp * 3 + bufidx) * 16384 + w4 * 1024;
    char* dV = dK + 8192;
    gload16(sK, dK);
    gload16(sK + 4096, dK + 4096);
    gload16(sV, dV);
    gload16(sV + (size_t)32 * SEQ * 2, dV + 4096);
  };

  auto qkt = [&](const bf16x8 (&kf)[2][4], const bf16x8 (&qft)[2][2],
                 f32x4 (&st)[2][4]) {
    __builtin_amdgcn_s_setprio(1);
#pragma unroll
    for (int ks = 0; ks < 2; ++ks)
#pragma unroll
      for (int g = 0; g < 4; ++g) {
        st[0][g] = __builtin_amdgcn_mfma_f32_16x16x32_bf16(kf[ks][g], qft[0][ks], st[0][g], 0, 0, 0);
        st[1][g] = __builtin_amdgcn_mfma_f32_16x16x32_bf16(kf[ks][g], qft[1][ks], st[1][g], 0, 0, 0);
      }
    __builtin_amdgcn_s_setprio(0);
  };

  auto sm_pv = [&](f32x4 (&st)[2][4], float (&lat)[2], f32x4 (&oat)[2][4],
                   const bf16x8 (&vf)[2][4]) {
#pragma unroll
    for (int qm = 0; qm < 2; ++qm)
#pragma unroll
      for (int g = 0; g < 4; ++g) {
        f32x4 s4 = st[qm][g];
        float p0 = __builtin_amdgcn_exp2f(s4.x);
        float p1 = __builtin_amdgcn_exp2f(s4.y);
        float p2 = __builtin_amdgcn_exp2f(s4.z);
        float p3 = __builtin_amdgcn_exp2f(s4.w);
        lat[qm] += (p0 + p1) + (p2 + p3);
        uint off = (uint)((qm * 16 + lm) * 128 + ((g * 32 + lw * 8) ^ (l7 << 4)));
        *reinterpret_cast<uint*>(Pbase + off)     = pack_bf16(p0, p1);
        *reinterpret_cast<uint*>(Pbase + off + 4) = pack_bf16(p2, p3);
      }
    bf16x8 pf[2][2];
#pragma unroll
    for (int qm = 0; qm < 2; ++qm)
#pragma unroll
      for (int ks = 0; ks < 2; ++ks)
        pf[qm][ks] = *reinterpret_cast<const bf16x8*>(
            Pbase + (qm * 16 + lm) * 128 + ((lw * 16 + ks * 64) ^ (l7 << 4)));
    __builtin_amdgcn_s_setprio(1);
#pragma unroll
    for (int ks = 0; ks < 2; ++ks)
#pragma unroll
      for (int dn = 0; dn < 4; ++dn) {
        oat[0][dn] = __builtin_amdgcn_mfma_f32_16x16x32_bf16(vf[ks][dn], pf[0][ks], oat[0][dn], 0, 0, 0);
        oat[1][dn] = __builtin_amdgcn_mfma_f32_16x16x32_bf16(vf[ks][dn], pf[1][ks], oat[1][dn], 0, 0, 0);
      }
    __builtin_amdgcn_s_setprio(0);
  };

  // prologue: group g stages its tiles #0 (kb=g) and #1 (kb=g+2)
  stage(grp, 0);
  stage(grp + 2, 1);

  for (int i = 0; i < iters; ++i) {
    const int bufidx = i % 3;
    if (i + 1 < iters) asm volatile("s_waitcnt vmcnt(4)" ::: "memory");
    else               asm volatile("s_waitcnt vmcnt(0)" ::: "memory");
    __builtin_amdgcn_s_barrier();
    __builtin_amdgcn_sched_barrier(0);
    if (i + 2 < iters) stage(2 * (i + 2) + grp, (i + 2) % 3);
    const char* Kb = smem + (grp * 3 + bufidx) * 16384;
    const char* Vb = Kb + 8192;

    bf16x8 kf[2][4];
#pragma unroll
    for (int ks = 0; ks < 2; ++ks)
#pragma unroll
      for (int g = 0; g < 4; ++g)
        kf[ks][g] = *reinterpret_cast<const bf16x8*>(
            Kb + (g * 16 + lm) * 128 + ((lw * 16 + ks * 64) ^ (l7 << 4)));

    f32x4 stA[2][4] = {};
    qkt(kf, qf[0], stA);

    bf16x8 vf[2][4];
#pragma unroll
    for (int ks = 0; ks < 2; ++ks)
#pragma unroll
      for (int dn = 0; dn < 4; ++dn)
        vf[ks][dn] = *reinterpret_cast<const bf16x8*>(
            Vb + (dn * 16 + lm) * 128 + ((lw * 16 + ks * 64) ^ (l7 << 4)));

    sm_pv(stA, l_acc[0], oacc[0], vf);

    if (i < bIters) {
      f32x4 stB[2][4] = {};
      qkt(kf, qf[1], stB);
      sm_pv(stB, l_acc[1], oacc[1], vf);
    }
  }

  // merge group partials: group1 -> LDS, group0 adds (slot-major, 16B/lane).
  __syncthreads();
  if (grp == 1) {
#pragma unroll
    for (int tq = 0; tq < 2; ++tq)
#pragma unroll
      for (int qm = 0; qm < 2; ++qm)
#pragma unroll
        for (int dn = 0; dn < 4; ++dn)
          *reinterpret_cast<f32x4*>(
              smem + ((tq * 2 + qm) * 4 + dn) * 4096 + (w4 * 64 + l) * 16) = oacc[tq][qm][dn];
    float4 lv{l_acc[0][0], l_acc[0][1], l_acc[1][0], l_acc[1][1]};
    *reinterpret_cast<float4*>(smem + 65536 + (w4 * 64 + l) * 16) = lv;
  }
  __syncthreads();
  if (grp == 0) {
#pragma unroll
    for (int tq = 0; tq < 2; ++tq)
#pragma unroll
      for (int qm = 0; qm < 2; ++qm)
#pragma unroll
        for (int dn = 0; dn < 4; ++dn)
          oacc[tq][qm][dn] += *reinterpret_cast<const f32x4*>(
              smem + ((tq * 2 + qm) * 4 + dn) * 4096 + (w4 * 64 + l) * 16);
    float4 lv = *reinterpret_cast<const float4*>(smem + 65536 + (w4 * 64 + l) * 16);
    l_acc[0][0] += lv.x; l_acc[0][1] += lv.y; l_acc[1][0] += lv.z; l_acc[1][1] += lv.w;

#pragma unroll
    for (int tq = 0; tq < 2; ++tq) {
      const int qb = tq ? qbB : qbA;
#pragma unroll
      for (int qm = 0; qm < 2; ++qm) {
        float ls = (tq ? l_acc[1] : l_acc[0])[qm];
        ls += __shfl_xor(ls, 16);
        ls += __shfl_xor(ls, 32);
        float inv = 1.f / ls;
        const int qg = qb * 128 + w4 * 32 + qm * 16 + lm;
#pragma unroll
        for (int dn = 0; dn < 4; ++dn) {
          f32x4 o = (tq ? oacc[1] : oacc[0])[qm][dn];
          o *= inv;
          size_t off = ((size_t)b * SEQ + qg) * DIM + h * HD + dn * 16 + lw * 4;
          uint2 uo{(uint)f2h(o[0]) | ((uint)f2h(o[1]) << 16),
                   (uint)f2h(o[2]) | ((uint)f2h(o[3]) << 16)};
          *reinterpret_cast<uint2*>(&aout[off]) = uo;
        }
      }
    }
  }
}

// ---------------- launch -----------------------------------------------------
extern "C" void kernel_launch(void* const* d_in, const int* in_sizes, int n_in,
                              void* d_out, int out_size, void* d_ws, size_t ws_size,
                              hipStream_t stream) {
  const float* x       = (const float*)d_in[0];
  const float* Wqkv    = (const float*)d_in[1];
  const float* Wout    = (const float*)d_in[2];
  const float* q_scale = (const float*)d_in[3];
  const float* k_scale = (const float*)d_in[4];
  float* out = (float*)d_out;

  char* ws = (char*)d_ws;
  ushort_t* qkv = (ushort_t*)ws;                           // 25.2 MB bf16
  ushort_t* attn_f16 = (ushort_t*)ws;                      // reuse qkv region
  size_t off = (size_t)MROW * N3 * 2;
  ushort_t* qT = (ushort_t*)(ws + off); off += (size_t)NB * NH * SEQ * HD * 2;
  ushort_t* kT = (ushort_t*)(ws + off); off += (size_t)NB * NH * SEQ * HD * 2;
  ushort_t* vT = (ushort_t*)(ws + off); off += (size_t)NB * NH * SEQ * HD * 2;
  float* tab   = (float*)(ws + off);    off += (size_t)SEQ * 64 * 4;
  ushort_t* xh   = (ushort_t*)(ws + off); off += (size_t)MROW * DIM * 2;
  ushort_t* wqh  = (ushort_t*)(ws + off); off += (size_t)N3 * DIM * 2;
  ushort_t* wo16 = (ushort_t*)(ws + off);

  rope_table_kernel<<<dim3(SEQ * 32 / 256), dim3(256), 0, stream>>>(tab);
  cvt_bf16_kernel<<<dim3(MROW * DIM / 4 / 256), dim3(256), 0, stream>>>(x, xh, MROW * DIM / 4);
  cvt_bf16_kernel<<<dim3(N3 * DIM / 4 / 256), dim3(256), 0, stream>>>(Wqkv, wqh, N3 * DIM / 4);
  cvt_f16_kernel<<<dim3(DIM * DIM / 4 / 256), dim3(256), 0, stream>>>(Wout, wo16, DIM * DIM / 4);
  gemm_mfma_kernel<128, false, true, false><<<dim3(N3 / 128, MROW / 128), dim3(256), 0, stream>>>(
      xh, nullptr, wqh, nullptr, qkv, N3, DIM);
  qkv_post_kernel<<<dim3(NB * 32 * NH), dim3(256), 0, stream>>>(qkv, q_scale, k_scale, tab, qT, kT, vT);
  attn_mfma_kernel<<<dim3(8, NB * NH), dim3(512), 0, stream>>>(qT, kT, vT, attn_f16);
  gemm_mfma_kernel<128, false, false, true><<<dim3(DIM / 128, MROW / 128), dim3(256), 0, stream>>>(
      attn_f16, nullptr, wo16, nullptr, out, DIM, DIM);
}

// Round 11
// 107.435 us; speedup vs baseline: 2.0583x; 1.0974x over previous
//
#include <hip/hip_runtime.h>
#include <hip/hip_bf16.h>
#include <cstddef>

typedef unsigned int uint;
typedef unsigned short ushort_t;
typedef __attribute__((ext_vector_type(8))) short bf16x8;
typedef __attribute__((ext_vector_type(8))) _Float16 f16x8;
typedef __attribute__((ext_vector_type(4))) float f32x4;

constexpr int NB   = 2;
constexpr int NP   = 256;
constexpr int DIM  = 1024;
constexpr int NH   = 16;
constexpr int HD   = 64;
constexpr int SEQ  = 2048;
constexpr int MROW = NB * SEQ;      // 4096
constexpr int N3   = 3 * DIM;       // 3072
// softmax in base-2: fold hd^-0.5 * log2(e) into q
constexpr float QS = 0.125f * 1.4426950408889634f;

__device__ __forceinline__ ushort_t f2bf(float x) {
  uint u = __builtin_bit_cast(uint, x);
  u = (u + 0x7fff + ((u >> 16) & 1)) >> 16;   // round-to-nearest-even
  return (ushort_t)u;
}
__device__ __forceinline__ uint pack_bf16(float a, float b) {
  __hip_bfloat162 h = __float22bfloat162_rn(float2{a, b});
  uint u; __builtin_memcpy(&u, &h, 4);        // v_cvt_pk_bf16_f32
  return u;
}
__device__ __forceinline__ float bf2f(ushort_t h) {
  return __builtin_bit_cast(float, (uint)h << 16);
}
__device__ __forceinline__ ushort_t f2h(float x) {
  _Float16 h = (_Float16)x;
  ushort_t u; __builtin_memcpy(&u, &h, 2);
  return u;
}

template<bool F16>
__device__ __forceinline__ f32x4 mfma16(bf16x8 a, bf16x8 b, f32x4 c) {
  if constexpr (F16) {
    f16x8 af = __builtin_bit_cast(f16x8, a);
    f16x8 bf = __builtin_bit_cast(f16x8, b);
    return __builtin_amdgcn_mfma_f32_16x16x32_f16(af, bf, c, 0, 0, 0);
  } else {
    return __builtin_amdgcn_mfma_f32_16x16x32_bf16(a, b, c, 0, 0, 0);
  }
}

__device__ __forceinline__ void gload16(const void* g, void* l) {
  __builtin_amdgcn_global_load_lds((const __attribute__((address_space(1))) uint*)g,
                                   (__attribute__((address_space(3))) uint*)l, 16, 0, 0);
}

// ---------------- K0: fused prep: cvt x->bf16, Wqkv->bf16, Wout->f16, RoPE tab
__global__ __launch_bounds__(256) void prep_kernel(
    const float* __restrict__ x, const float* __restrict__ Wqkv,
    const float* __restrict__ Wout, ushort_t* __restrict__ xh,
    ushort_t* __restrict__ wqh, ushort_t* __restrict__ wo16,
    float* __restrict__ tab) {
  const int i = blockIdx.x * 256 + threadIdx.x;
  constexpr int NX = MROW * DIM / 4;   // 1048576
  constexpr int NQ = N3 * DIM / 4;     // 786432
  constexpr int NO = DIM * DIM / 4;    // 262144
  if (i < NX) {
    float4 v = reinterpret_cast<const float4*>(x)[i];
    uint2 o; o.x = pack_bf16(v.x, v.y); o.y = pack_bf16(v.z, v.w);
    reinterpret_cast<uint2*>(xh)[i] = o;
  }
  if (i < NQ) {
    float4 v = reinterpret_cast<const float4*>(Wqkv)[i];
    uint2 o; o.x = pack_bf16(v.x, v.y); o.y = pack_bf16(v.z, v.w);
    reinterpret_cast<uint2*>(wqh)[i] = o;
  }
  if (i < NO) {
    float4 v = reinterpret_cast<const float4*>(Wout)[i];
    uint2 o;
    o.x = (uint)f2h(v.x) | ((uint)f2h(v.y) << 16);
    o.y = (uint)f2h(v.z) | ((uint)f2h(v.w) << 16);
    reinterpret_cast<uint2*>(wo16)[i] = o;
  }
  if (i < SEQ * 32) {
    int l = i >> 5, ii = i & 31;
    float j = (float)(ii & 15);
    float invf = exp2f(-j * (13.287712379549449f / 16.f));
    float pos = (ii < 16) ? (float)(l >> 8) : (float)(l & (NP - 1));
    float ang = pos * invf;
    tab[i]            = cosf(ang);
    tab[SEQ * 32 + i] = sinf(ang);
  }
}

// ---------------- 16-bit MFMA GEMM: C[M][N] = A[M][K] * B[N][K]^T ------------
// 2-phase double-buffered: stage(t+1) issued BEFORE compute(t); single
// __syncthreads()/iter (its vmcnt(0) drain is exactly the wait for t+1).
template<int BM, bool BF16OUT, bool F16>
__global__ __launch_bounds__(256) void gemm_mfma_kernel(
    const ushort_t* __restrict__ A_, const ushort_t* __restrict__ B_,
    void* __restrict__ Cv, int N, int K) {
  constexpr int MF = BM / 32;               // m-frags per wave
  constexpr int PH = (BM + 128) * 128;      // bytes per phase
  __shared__ __align__(16) char smem[2 * PH];
  const int tid = threadIdx.x;
  const int l = tid & 63, w4 = tid >> 6;
  const int l7 = l & 7, l3 = l >> 3, lm = l & 15, lw = l >> 4;
  const int wm = w4 >> 1, wn = w4 & 1;
  const int bm = blockIdx.y * BM, bn = blockIdx.x * 128;
  const uint rloc = (uint)(w4 * 8 + l3);
  const uint csrc = (uint)((l7 ^ l3) << 4);
  const uint sw = (uint)(lm & 7);

  f32x4 acc[MF][4] = {};

  auto stageAB = [&](int dstoff, int k0) {
    const char* Ab = reinterpret_cast<const char*>(A_);
    const char* Bb = reinterpret_cast<const char*>(B_);
#pragma unroll
    for (int i = 0; i < BM / 32; ++i)
      gload16(Ab + (((size_t)(bm + i * 32 + rloc) * K + k0) << 1) + csrc,
              smem + dstoff + (i * 32 + w4 * 8) * 128);
#pragma unroll
    for (int i = 0; i < 4; ++i)
      gload16(Bb + (((size_t)(bn + i * 32 + rloc) * K + k0) << 1) + csrc,
              smem + dstoff + BM * 128 + (i * 32 + w4 * 8) * 128);
  };

  stageAB(0, 0);
  __syncthreads();

  int cur = 0;
  for (int k0 = 0; k0 < K; k0 += 64) {
    const int nxt = cur ^ 1;
    if (k0 + 64 < K) stageAB(nxt * PH, k0 + 64);
    const char* As = smem + cur * PH;
    const char* Bs = As + BM * 128;
    bf16x8 af[MF][2], bfr[4][2];
#pragma unroll
    for (int mi = 0; mi < MF; ++mi)
#pragma unroll
      for (int ks = 0; ks < 2; ++ks)
        af[mi][ks] = *reinterpret_cast<const bf16x8*>(
            As + (wm * (BM / 2) + mi * 16 + lm) * 128 + ((((uint)ks * 4 + lw) ^ sw) << 4));
#pragma unroll
    for (int ni = 0; ni < 4; ++ni)
#pragma unroll
      for (int ks = 0; ks < 2; ++ks)
        bfr[ni][ks] = *reinterpret_cast<const bf16x8*>(
            Bs + (wn * 64 + ni * 16 + lm) * 128 + ((((uint)ks * 4 + lw) ^ sw) << 4));
#pragma unroll
    for (int ks = 0; ks < 2; ++ks)
#pragma unroll
      for (int mi = 0; mi < MF; ++mi)
#pragma unroll
        for (int ni = 0; ni < 4; ++ni)
          acc[mi][ni] = mfma16<F16>(af[mi][ks], bfr[ni][ks], acc[mi][ni]);
    __syncthreads();   // drains vmcnt(0): next phase staged; cur readers done
    cur ^= 1;
  }
#pragma unroll
  for (int mi = 0; mi < MF; ++mi)
#pragma unroll
    for (int ni = 0; ni < 4; ++ni) {
      f32x4 a = acc[mi][ni];
      const int row0 = bm + wm * (BM / 2) + mi * 16 + lw * 4;
      const int col  = bn + wn * 64 + ni * 16 + lm;
      if constexpr (BF16OUT) {
        ushort_t* Cb = (ushort_t*)Cv;
#pragma unroll
        for (int r = 0; r < 4; ++r)
          Cb[(size_t)(row0 + r) * N + col] = f2bf(a[r]);
      } else {
        float* Cf = (float*)Cv;
#pragma unroll
        for (int r = 0; r < 4; ++r)
          Cf[(size_t)(row0 + r) * N + col] = a[r];
      }
    }
}

// ---------------- K2: RMSNorm + RoPE (bf16 in); qT/kT row-major, vT d-major --
__global__ __launch_bounds__(256) void qkv_post_kernel(
    const ushort_t* __restrict__ qkv, const float* __restrict__ qs,
    const float* __restrict__ ksc, const float* __restrict__ tab,
    ushort_t* __restrict__ qT, ushort_t* __restrict__ kT, ushort_t* __restrict__ vT) {
  __shared__ ushort_t vt[64][72];
  const int bx = blockIdx.x;
  const int h = bx & 15, lt = (bx >> 4) & 31, b = bx >> 9;
  const int t = threadIdx.x, lr = t >> 2, s = t & 3, d0 = s * 16;
  const int lg = lt * 64 + lr;
  const int bh = b * NH + h;
  const ushort_t* rowp = qkv + ((size_t)(b * SEQ + lg) * N3) + h * HD + d0;

  ushort_t qraw[16], kraw[16], vraw[16];
  *reinterpret_cast<uint4*>(&qraw[0]) = *reinterpret_cast<const uint4*>(rowp);
  *reinterpret_cast<uint4*>(&qraw[8]) = *reinterpret_cast<const uint4*>(rowp + 8);
  *reinterpret_cast<uint4*>(&kraw[0]) = *reinterpret_cast<const uint4*>(rowp + DIM);
  *reinterpret_cast<uint4*>(&kraw[8]) = *reinterpret_cast<const uint4*>(rowp + DIM + 8);
  *reinterpret_cast<uint4*>(&vraw[0]) = *reinterpret_cast<const uint4*>(rowp + 2 * DIM);
  *reinterpret_cast<uint4*>(&vraw[8]) = *reinterpret_cast<const uint4*>(rowp + 2 * DIM + 8);
  float4 qs4[4], ks4[4];
#pragma unroll
  for (int u = 0; u < 4; ++u) {
    qs4[u] = *reinterpret_cast<const float4*>(qs + d0 + u * 4);
    ks4[u] = *reinterpret_cast<const float4*>(ksc + d0 + u * 4);
  }
  const float* sq_ = reinterpret_cast<const float*>(qs4);
  const float* sk_ = reinterpret_cast<const float*>(ks4);
  float vq[16], vk[16];
#pragma unroll
  for (int j = 0; j < 16; ++j) { vq[j] = bf2f(qraw[j]); vk[j] = bf2f(kraw[j]); }

  float sq = 0.f, sk = 0.f;
#pragma unroll
  for (int j = 0; j < 16; ++j) { sq = fmaf(vq[j], vq[j], sq); sk = fmaf(vk[j], vk[j], sk); }
  sq += __shfl_xor(sq, 1); sq += __shfl_xor(sq, 2);
  sk += __shfl_xor(sk, 1); sk += __shfl_xor(sk, 2);
  float rq = rsqrtf(sq * (1.f / HD) + 1e-6f);
  float rk = rsqrtf(sk * (1.f / HD) + 1e-6f);

  float4 c4[2], s4[2];
  const float* tc = tab + (size_t)lg * 32 + s * 8;
  const float* ts = tab + (size_t)SEQ * 32 + (size_t)lg * 32 + s * 8;
  c4[0] = *reinterpret_cast<const float4*>(tc);
  c4[1] = *reinterpret_cast<const float4*>(tc + 4);
  s4[0] = *reinterpret_cast<const float4*>(ts);
  s4[1] = *reinterpret_cast<const float4*>(ts + 4);
  const float* cj = reinterpret_cast<const float*>(c4);
  const float* sj = reinterpret_cast<const float*>(s4);

  uint uq[8], uk[8], uv[8];
#pragma unroll
  for (int j = 0; j < 8; ++j) {
    float qe = vq[2*j] * rq * sq_[2*j], qo = vq[2*j+1] * rq * sq_[2*j+1];
    float ke = vk[2*j] * rk * sk_[2*j], ko = vk[2*j+1] * rk * sk_[2*j+1];
    float c = cj[j], sn = sj[j];
    uq[j] = pack_bf16((qe * c - qo * sn) * QS, (qe * sn + qo * c) * QS);
    uk[j] = pack_bf16(ke * c - ko * sn, ke * sn + ko * c);
    uv[j] = (uint)vraw[2*j] | ((uint)vraw[2*j+1] << 16);
  }
  ushort_t* qp = qT + ((size_t)bh * SEQ + lg) * HD + d0;
  ushort_t* kp = kT + ((size_t)bh * SEQ + lg) * HD + d0;
  reinterpret_cast<uint4*>(qp)[0] = *reinterpret_cast<uint4*>(&uq[0]);
  reinterpret_cast<uint4*>(qp)[1] = *reinterpret_cast<uint4*>(&uq[4]);
  reinterpret_cast<uint4*>(kp)[0] = *reinterpret_cast<uint4*>(&uk[0]);
  reinterpret_cast<uint4*>(kp)[1] = *reinterpret_cast<uint4*>(&uk[4]);
#pragma unroll
  for (int j = 0; j < 16; ++j)
    vt[d0 + j][lr] = (ushort_t)((j & 1) ? (uv[j >> 1] >> 16) : (uv[j >> 1] & 0xffff));
  __syncthreads();
  const int drow = t >> 2, lc = (t & 3) * 16;
  ushort_t* vp = vT + ((size_t)bh * HD + drow) * SEQ + lt * 64 + lc;
  reinterpret_cast<uint4*>(vp)[0] = *reinterpret_cast<const uint4*>(&vt[drow][lc]);
  reinterpret_cast<uint4*>(vp)[1] = *reinterpret_cast<const uint4*>(&vt[drow][lc + 8]);
}

// ---------------- K3: bf16 MFMA block-causal flash attention -----------------
// 64-row q-tile pairs (31-p, p) -> 512 blocks; 8 waves (2 k-split groups of 4);
// 2-buf/group gemm-style 2-phase pipeline; per-wave 2K P; LDS exactly 80K ->
// 2 blocks/CU = 4 waves/SIMD. Math order per q-row identical to R8/R10.
__global__ __launch_bounds__(512, 4) void attn_mfma_kernel(
    const ushort_t* __restrict__ qT, const ushort_t* __restrict__ kT,
    const ushort_t* __restrict__ vT, ushort_t* __restrict__ aout) {
  __shared__ __align__(16) char smem[81920];  // 4x16K KV bufs + 8x2K P
  const int tid = threadIdx.x;
  const int l  = tid & 63, w8 = tid >> 6;
  const int grp = w8 >> 2, w4 = w8 & 3;
  const int lm = l & 15, lw = l >> 4, l7 = l & 7, l3 = l >> 3;
  const int bh = blockIdx.y, b = bh >> 4, h = bh & 15;
  const int p = blockIdx.x;                    // 0..15
  const int qbA = 31 - p, qbB = p;             // 64-row q-tile indices
  const int nkbA = ((qbA >> 2) + 1) * 4;       // 20..32
  const int nkbB = ((qbB >> 2) + 1) * 4;       // 4..16 (prefix of A's range)
  const int iters  = nkbA >> 1;                // per-group iterations
  const int bIters = nkbB >> 1;

  bf16x8 qf[2][2];                             // [tile][ks], 16 q-rows per wave
#pragma unroll
  for (int tq = 0; tq < 2; ++tq) {
    const size_t qrow0 = (size_t)bh * SEQ + (tq ? qbB : qbA) * 64 + w4 * 16;
#pragma unroll
    for (int ks = 0; ks < 2; ++ks)
      qf[tq][ks] = *reinterpret_cast<const bf16x8*>(
          qT + (qrow0 + lm) * HD + lw * 8 + ks * 32);
  }

  const char* kTb = reinterpret_cast<const char*>(kT + (size_t)bh * SEQ * HD);
  const char* vTb = reinterpret_cast<const char*>(vT + (size_t)bh * HD * SEQ);
  const uint rloc = (uint)(w4 * 8 + l3);
  const uint csrc = (uint)((l7 ^ l3) << 4);
  char* Pbase = smem + 65536 + w8 * 2048;

  float l_acc[2] = {};
  f32x4 oacc[2][4] = {};

  auto stage = [&](int kb, int bufidx) {
    const char* sK = kTb + ((size_t)(kb * 64) + rloc) * 128 + csrc;
    const char* sV = vTb + (size_t)rloc * (SEQ * 2) + (size_t)kb * 128 + csrc;
    char* dK = smem + (grp * 2 + bufidx) * 16384 + w4 * 1024;
    char* dV = dK + 8192;
    gload16(sK, dK);
    gload16(sK + 4096, dK + 4096);
    gload16(sV, dV);
    gload16(sV + (size_t)32 * SEQ * 2, dV + 4096);
  };

  // one q-tile (16 rows/wave) vs staged 64-kv tile
  auto phase = [&](const char* Kb, const char* Vb, const bf16x8 (&qft)[2],
                   float& lat, f32x4 (&oat)[4]) {
    bf16x8 kf[2][4];
#pragma unroll
    for (int ks = 0; ks < 2; ++ks)
#pragma unroll
      for (int g = 0; g < 4; ++g)
        kf[ks][g] = *reinterpret_cast<const bf16x8*>(
            Kb + (g * 16 + lm) * 128 + ((lw * 16 + ks * 64) ^ (l7 << 4)));
    f32x4 st[4] = {};
    __builtin_amdgcn_s_setprio(1);
#pragma unroll
    for (int ks = 0; ks < 2; ++ks)
#pragma unroll
      for (int g = 0; g < 4; ++g)
        st[g] = __builtin_amdgcn_mfma_f32_16x16x32_bf16(kf[ks][g], qft[ks], st[g], 0, 0, 0);
    __builtin_amdgcn_s_setprio(0);
#pragma unroll
    for (int g = 0; g < 4; ++g) {
      f32x4 s4 = st[g];
      float p0 = __builtin_amdgcn_exp2f(s4.x);
      float p1 = __builtin_amdgcn_exp2f(s4.y);
      float p2 = __builtin_amdgcn_exp2f(s4.z);
      float p3 = __builtin_amdgcn_exp2f(s4.w);
      lat += (p0 + p1) + (p2 + p3);
      uint off = (uint)(lm * 128 + ((g * 32 + lw * 8) ^ (l7 << 4)));
      *reinterpret_cast<uint*>(Pbase + off)     = pack_bf16(p0, p1);
      *reinterpret_cast<uint*>(Pbase + off + 4) = pack_bf16(p2, p3);
    }
    // vf loads issued between P write and P read: covers LDS turnaround
    bf16x8 vf[2][4];
#pragma unroll
    for (int ks = 0; ks < 2; ++ks)
#pragma unroll
      for (int dn = 0; dn < 4; ++dn)
        vf[ks][dn] = *reinterpret_cast<const bf16x8*>(
            Vb + (dn * 16 + lm) * 128 + ((lw * 16 + ks * 64) ^ (l7 << 4)));
    bf16x8 pf[2];
#pragma unroll
    for (int ks = 0; ks < 2; ++ks)
      pf[ks] = *reinterpret_cast<const bf16x8*>(
          Pbase + lm * 128 + ((lw * 16 + ks * 64) ^ (l7 << 4)));
    __builtin_amdgcn_s_setprio(1);
#pragma unroll
    for (int ks = 0; ks < 2; ++ks)
#pragma unroll
      for (int dn = 0; dn < 4; ++dn)
        oat[dn] = __builtin_amdgcn_mfma_f32_16x16x32_bf16(vf[ks][dn], pf[ks], oat[dn], 0, 0, 0);
    __builtin_amdgcn_s_setprio(0);
  };

  stage(grp, 0);
  __syncthreads();
  int cur = 0;
  for (int i = 0; i < iters; ++i) {
    if (i + 1 < iters) stage(2 * (i + 1) + grp, cur ^ 1);
    const char* Kb = smem + (grp * 2 + cur) * 16384;
    const char* Vb = Kb + 8192;
    phase(Kb, Vb, qf[0], l_acc[0], oacc[0]);
    if (i < bIters) phase(Kb, Vb, qf[1], l_acc[1], oacc[1]);
    __syncthreads();   // drains vmcnt(0): next tile staged; cur readers done
    cur ^= 1;
  }

  // merge group partials: group1 -> LDS (KV region dead), group0 adds.
  if (grp == 1) {
#pragma unroll
    for (int tq = 0; tq < 2; ++tq)
#pragma unroll
      for (int dn = 0; dn < 4; ++dn)
        *reinterpret_cast<f32x4*>(
            smem + (tq * 4 + dn) * 4096 + (w4 * 64 + l) * 16) = oacc[tq][dn];
    float2 lv{l_acc[0], l_acc[1]};
    *reinterpret_cast<float2*>(smem + 32768 + (w4 * 64 + l) * 8) = lv;
  }
  __syncthreads();
  if (grp == 0) {
#pragma unroll
    for (int tq = 0; tq < 2; ++tq)
#pragma unroll
      for (int dn = 0; dn < 4; ++dn)
        oacc[tq][dn] += *reinterpret_cast<const f32x4*>(
            smem + (tq * 4 + dn) * 4096 + (w4 * 64 + l) * 16);
    float2 lv = *reinterpret_cast<const float2*>(smem + 32768 + (w4 * 64 + l) * 8);
    l_acc[0] += lv.x; l_acc[1] += lv.y;

#pragma unroll
    for (int tq = 0; tq < 2; ++tq) {
      const int qb = tq ? qbB : qbA;
      float ls = l_acc[tq];
      ls += __shfl_xor(ls, 16);
      ls += __shfl_xor(ls, 32);
      float inv = 1.f / ls;
      const int qg = qb * 64 + w4 * 16 + lm;
#pragma unroll
      for (int dn = 0; dn < 4; ++dn) {
        f32x4 o = oacc[tq][dn];
        o *= inv;
        size_t off = ((size_t)b * SEQ + qg) * DIM + h * HD + dn * 16 + lw * 4;
        uint2 uo{(uint)f2h(o[0]) | ((uint)f2h(o[1]) << 16),
                 (uint)f2h(o[2]) | ((uint)f2h(o[3]) << 16)};
        *reinterpret_cast<uint2*>(&aout[off]) = uo;
      }
    }
  }
}

// ---------------- launch -----------------------------------------------------
extern "C" void kernel_launch(void* const* d_in, const int* in_sizes, int n_in,
                              void* d_out, int out_size, void* d_ws, size_t ws_size,
                              hipStream_t stream) {
  const float* x       = (const float*)d_in[0];
  const float* Wqkv    = (const float*)d_in[1];
  const float* Wout    = (const float*)d_in[2];
  const float* q_scale = (const float*)d_in[3];
  const float* k_scale = (const float*)d_in[4];
  float* out = (float*)d_out;

  char* ws = (char*)d_ws;
  ushort_t* qkv = (ushort_t*)ws;                           // 25.2 MB bf16
  ushort_t* attn_f16 = (ushort_t*)ws;                      // reuse qkv region
  size_t off = (size_t)MROW * N3 * 2;
  ushort_t* qT = (ushort_t*)(ws + off); off += (size_t)NB * NH * SEQ * HD * 2;
  ushort_t* kT = (ushort_t*)(ws + off); off += (size_t)NB * NH * SEQ * HD * 2;
  ushort_t* vT = (ushort_t*)(ws + off); off += (size_t)NB * NH * SEQ * HD * 2;
  float* tab   = (float*)(ws + off);    off += (size_t)SEQ * 64 * 4;
  ushort_t* xh   = (ushort_t*)(ws + off); off += (size_t)MROW * DIM * 2;
  ushort_t* wqh  = (ushort_t*)(ws + off); off += (size_t)N3 * DIM * 2;
  ushort_t* wo16 = (ushort_t*)(ws + off);

  prep_kernel<<<dim3(MROW * DIM / 4 / 256), dim3(256), 0, stream>>>(
      x, Wqkv, Wout, xh, wqh, wo16, tab);
  gemm_mfma_kernel<128, true, false><<<dim3(N3 / 128, MROW / 128), dim3(256), 0, stream>>>(
      xh, wqh, qkv, N3, DIM);
  qkv_post_kernel<<<dim3(NB * 32 * NH), dim3(256), 0, stream>>>(qkv, q_scale, k_scale, tab, qT, kT, vT);
  attn_mfma_kernel<<<dim3(16, NB * NH), dim3(512), 0, stream>>>(qT, kT, vT, attn_f16);
  gemm_mfma_kernel<128, false, true><<<dim3(DIM / 128, MROW / 128), dim3(256), 0, stream>>>(
      attn_f16, wo16, out, DIM, DIM);
}

// Round 12
// 101.246 us; speedup vs baseline: 2.1841x; 1.0611x over previous
//
#include <hip/hip_runtime.h>
#include <hip/hip_bf16.h>
#include <cstddef>

typedef unsigned int uint;
typedef unsigned short ushort_t;
typedef __attribute__((ext_vector_type(8))) short bf16x8;
typedef __attribute__((ext_vector_type(8))) _Float16 f16x8;
typedef __attribute__((ext_vector_type(4))) float f32x4;

constexpr int NB   = 2;
constexpr int NP   = 256;
constexpr int DIM  = 1024;
constexpr int NH   = 16;
constexpr int HD   = 64;
constexpr int SEQ  = 2048;
constexpr int MROW = NB * SEQ;      // 4096
constexpr int N3   = 3 * DIM;       // 3072
// softmax in base-2: fold hd^-0.5 * log2(e) into q
constexpr float QS = 0.125f * 1.4426950408889634f;

__device__ __forceinline__ ushort_t f2bf(float x) {
  uint u = __builtin_bit_cast(uint, x);
  u = (u + 0x7fff + ((u >> 16) & 1)) >> 16;   // round-to-nearest-even
  return (ushort_t)u;
}
__device__ __forceinline__ uint pack_bf16(float a, float b) {
  __hip_bfloat162 h = __float22bfloat162_rn(float2{a, b});
  uint u; __builtin_memcpy(&u, &h, 4);        // v_cvt_pk_bf16_f32
  return u;
}
__device__ __forceinline__ float bf2f(ushort_t h) {
  return __builtin_bit_cast(float, (uint)h << 16);
}
__device__ __forceinline__ ushort_t f2h(float x) {
  _Float16 h = (_Float16)x;
  ushort_t u; __builtin_memcpy(&u, &h, 2);
  return u;
}

template<bool F16>
__device__ __forceinline__ f32x4 mfma16(bf16x8 a, bf16x8 b, f32x4 c) {
  if constexpr (F16) {
    f16x8 af = __builtin_bit_cast(f16x8, a);
    f16x8 bf = __builtin_bit_cast(f16x8, b);
    return __builtin_amdgcn_mfma_f32_16x16x32_f16(af, bf, c, 0, 0, 0);
  } else {
    return __builtin_amdgcn_mfma_f32_16x16x32_bf16(a, b, c, 0, 0, 0);
  }
}

__device__ __forceinline__ void gload16(const void* g, void* l) {
  __builtin_amdgcn_global_load_lds((const __attribute__((address_space(1))) uint*)g,
                                   (__attribute__((address_space(3))) uint*)l, 16, 0, 0);
}

// ---------------- K0: fused prep: cvt x->bf16, Wqkv->bf16, Wout->f16, RoPE tab
__global__ __launch_bounds__(256) void prep_kernel(
    const float* __restrict__ x, const float* __restrict__ Wqkv,
    const float* __restrict__ Wout, ushort_t* __restrict__ xh,
    ushort_t* __restrict__ wqh, ushort_t* __restrict__ wo16,
    float* __restrict__ tab) {
  const int i = blockIdx.x * 256 + threadIdx.x;
  constexpr int NX = MROW * DIM / 4;   // 1048576
  constexpr int NQ = N3 * DIM / 4;     // 786432
  constexpr int NO = DIM * DIM / 4;    // 262144
  if (i < NX) {
    float4 v = reinterpret_cast<const float4*>(x)[i];
    uint2 o; o.x = pack_bf16(v.x, v.y); o.y = pack_bf16(v.z, v.w);
    reinterpret_cast<uint2*>(xh)[i] = o;
  }
  if (i < NQ) {
    float4 v = reinterpret_cast<const float4*>(Wqkv)[i];
    uint2 o; o.x = pack_bf16(v.x, v.y); o.y = pack_bf16(v.z, v.w);
    reinterpret_cast<uint2*>(wqh)[i] = o;
  }
  if (i < NO) {
    float4 v = reinterpret_cast<const float4*>(Wout)[i];
    uint2 o;
    o.x = (uint)f2h(v.x) | ((uint)f2h(v.y) << 16);
    o.y = (uint)f2h(v.z) | ((uint)f2h(v.w) << 16);
    reinterpret_cast<uint2*>(wo16)[i] = o;
  }
  if (i < SEQ * 32) {
    int l = i >> 5, ii = i & 31;
    float j = (float)(ii & 15);
    float invf = exp2f(-j * (13.287712379549449f / 16.f));
    float pos = (ii < 16) ? (float)(l >> 8) : (float)(l & (NP - 1));
    float ang = pos * invf;
    tab[i]            = cosf(ang);
    tab[SEQ * 32 + i] = sinf(ang);
  }
}

// ---------------- K1: QKV GEMM with FUSED RMSNorm+RoPE+transpose epilogue ----
// Main loop = proven 2-phase 128x128 BK=64 structure. Epilogue: each wave's
// wn-half spans exactly one 64-col head -> RMSNorm via 4 squares + shfl_xor
// 1/2/4/8 over the lm-group; RoPE pair via shfl_xor(n,1); v-blocks transpose
// through LDS (smem dead after main loop). Kills the 50MB qkv round-trip.
__global__ __launch_bounds__(256) void gemm_qkv_kernel(
    const ushort_t* __restrict__ A_, const ushort_t* __restrict__ B_,
    const float* __restrict__ qs, const float* __restrict__ ksc,
    const float* __restrict__ tab, ushort_t* __restrict__ qT,
    ushort_t* __restrict__ kT, ushort_t* __restrict__ vT) {
  constexpr int BM = 128, K = DIM;
  constexpr int PH = (BM + 128) * 128;      // bytes per phase
  __shared__ __align__(16) char smem[2 * PH];
  const int tid = threadIdx.x;
  const int l = tid & 63, w4 = tid >> 6;
  const int l7 = l & 7, l3 = l >> 3, lm = l & 15, lw = l >> 4;
  const int wm = w4 >> 1, wn = w4 & 1;
  const int bm = blockIdx.y * BM, bn = blockIdx.x * 128;
  const uint rloc = (uint)(w4 * 8 + l3);
  const uint csrc = (uint)((l7 ^ l3) << 4);
  const uint sw = (uint)(lm & 7);

  f32x4 acc[4][4] = {};

  auto stageAB = [&](int dstoff, int k0) {
    const char* Ab = reinterpret_cast<const char*>(A_);
    const char* Bb = reinterpret_cast<const char*>(B_);
#pragma unroll
    for (int i = 0; i < 4; ++i)
      gload16(Ab + (((size_t)(bm + i * 32 + rloc) * K + k0) << 1) + csrc,
              smem + dstoff + (i * 32 + w4 * 8) * 128);
#pragma unroll
    for (int i = 0; i < 4; ++i)
      gload16(Bb + (((size_t)(bn + i * 32 + rloc) * K + k0) << 1) + csrc,
              smem + dstoff + BM * 128 + (i * 32 + w4 * 8) * 128);
  };

  stageAB(0, 0);
  __syncthreads();
  int cur = 0;
  for (int k0 = 0; k0 < K; k0 += 64) {
    if (k0 + 64 < K) stageAB((cur ^ 1) * PH, k0 + 64);
    const char* As = smem + cur * PH;
    const char* Bs = As + BM * 128;
    bf16x8 af[4][2], bfr[4][2];
#pragma unroll
    for (int mi = 0; mi < 4; ++mi)
#pragma unroll
      for (int ks = 0; ks < 2; ++ks)
        af[mi][ks] = *reinterpret_cast<const bf16x8*>(
            As + (wm * 64 + mi * 16 + lm) * 128 + ((((uint)ks * 4 + lw) ^ sw) << 4));
#pragma unroll
    for (int ni = 0; ni < 4; ++ni)
#pragma unroll
      for (int ks = 0; ks < 2; ++ks)
        bfr[ni][ks] = *reinterpret_cast<const bf16x8*>(
            Bs + (wn * 64 + ni * 16 + lm) * 128 + ((((uint)ks * 4 + lw) ^ sw) << 4));
#pragma unroll
    for (int ks = 0; ks < 2; ++ks)
#pragma unroll
      for (int mi = 0; mi < 4; ++mi)
#pragma unroll
        for (int ni = 0; ni < 4; ++ni)
          acc[mi][ni] = __builtin_amdgcn_mfma_f32_16x16x32_bf16(
              af[mi][ks], bfr[ni][ks], acc[mi][ni], 0, 0, 0);
    __syncthreads();
    cur ^= 1;
  }

  const int sel = bn >> 10;                      // 0=q, 1=k, 2=v
  const int b   = bm >> 11;
  const int l0  = bm & (SEQ - 1);

  if (sel < 2) {
    const float* sc = (sel == 0) ? qs : ksc;
    ushort_t* dst   = (sel == 0) ? qT : kT;
    const int h   = ((bn & (DIM - 1)) >> 6) + wn;
    const int bhI = b * NH + h;
    float scv[4];
#pragma unroll
    for (int ni = 0; ni < 4; ++ni) scv[ni] = sc[ni * 16 + lm];
#pragma unroll
    for (int mi = 0; mi < 4; ++mi)
#pragma unroll
      for (int r = 0; r < 4; ++r) {
        const int lg = l0 + wm * 64 + mi * 16 + lw * 4 + r;
        float c0 = acc[mi][0][r], c1 = acc[mi][1][r];
        float c2 = acc[mi][2][r], c3 = acc[mi][3][r];
        float s = c0 * c0 + c1 * c1 + c2 * c2 + c3 * c3;
        s += __shfl_xor(s, 1); s += __shfl_xor(s, 2);
        s += __shfl_xor(s, 4); s += __shfl_xor(s, 8);
        float rms = rsqrtf(s * (1.f / HD) + 1e-6f);
        float cv[4] = {c0, c1, c2, c3};
#pragma unroll
        for (int ni = 0; ni < 4; ++ni) {
          float n  = cv[ni] * rms * scv[ni];
          float pr = __shfl_xor(n, 1);
          const int j = ni * 8 + (lm >> 1);
          float cz = tab[lg * 32 + j];
          float sz = tab[SEQ * 32 + lg * 32 + j];
          float o = (lm & 1) ? (pr * sz + n * cz) : (n * cz - pr * sz);
          if (sel == 0) o *= QS;
          dst[((size_t)bhI * SEQ + lg) * HD + ni * 16 + lm] = f2bf(o);
        }
      }
  } else {
    // v: stage bf16 into LDS [128][132], then transposed coalesced store
    ushort_t* vt = reinterpret_cast<ushort_t*>(smem);
#pragma unroll
    for (int mi = 0; mi < 4; ++mi)
#pragma unroll
      for (int ni = 0; ni < 4; ++ni)
#pragma unroll
        for (int r = 0; r < 4; ++r)
          vt[(wm * 64 + mi * 16 + lw * 4 + r) * 132 + wn * 64 + ni * 16 + lm] =
              f2bf(acc[mi][ni][r]);
    __syncthreads();
    const int d = tid >> 1, lc0 = (tid & 1) * 64;
    const int hv  = ((bn & (DIM - 1)) >> 6) + (d >> 6);
    const int dl  = d & 63;
    ushort_t* vp = vT + ((size_t)(b * NH + hv) * HD + dl) * SEQ + l0 + lc0;
#pragma unroll
    for (int u = 0; u < 8; ++u) {
      ushort_t t[8];
#pragma unroll
      for (int j = 0; j < 8; ++j) t[j] = vt[(lc0 + u * 8 + j) * 132 + d];
      uint4 w;
      w.x = (uint)t[0] | ((uint)t[1] << 16);
      w.y = (uint)t[2] | ((uint)t[3] << 16);
      w.z = (uint)t[4] | ((uint)t[5] << 16);
      w.w = (uint)t[6] | ((uint)t[7] << 16);
      reinterpret_cast<uint4*>(vp)[u] = w;
    }
  }
}

// ---------------- generic 16-bit MFMA GEMM (out-projection) ------------------
template<int BM, bool BF16OUT, bool F16>
__global__ __launch_bounds__(256) void gemm_mfma_kernel(
    const ushort_t* __restrict__ A_, const ushort_t* __restrict__ B_,
    void* __restrict__ Cv, int N, int K) {
  constexpr int MF = BM / 32;
  constexpr int PH = (BM + 128) * 128;
  __shared__ __align__(16) char smem[2 * PH];
  const int tid = threadIdx.x;
  const int l = tid & 63, w4 = tid >> 6;
  const int l7 = l & 7, l3 = l >> 3, lm = l & 15, lw = l >> 4;
  const int wm = w4 >> 1, wn = w4 & 1;
  const int bm = blockIdx.y * BM, bn = blockIdx.x * 128;
  const uint rloc = (uint)(w4 * 8 + l3);
  const uint csrc = (uint)((l7 ^ l3) << 4);
  const uint sw = (uint)(lm & 7);

  f32x4 acc[MF][4] = {};

  auto stageAB = [&](int dstoff, int k0) {
    const char* Ab = reinterpret_cast<const char*>(A_);
    const char* Bb = reinterpret_cast<const char*>(B_);
#pragma unroll
    for (int i = 0; i < BM / 32; ++i)
      gload16(Ab + (((size_t)(bm + i * 32 + rloc) * K + k0) << 1) + csrc,
              smem + dstoff + (i * 32 + w4 * 8) * 128);
#pragma unroll
    for (int i = 0; i < 4; ++i)
      gload16(Bb + (((size_t)(bn + i * 32 + rloc) * K + k0) << 1) + csrc,
              smem + dstoff + BM * 128 + (i * 32 + w4 * 8) * 128);
  };

  stageAB(0, 0);
  __syncthreads();

  int cur = 0;
  for (int k0 = 0; k0 < K; k0 += 64) {
    if (k0 + 64 < K) stageAB((cur ^ 1) * PH, k0 + 64);
    const char* As = smem + cur * PH;
    const char* Bs = As + BM * 128;
    bf16x8 af[MF][2], bfr[4][2];
#pragma unroll
    for (int mi = 0; mi < MF; ++mi)
#pragma unroll
      for (int ks = 0; ks < 2; ++ks)
        af[mi][ks] = *reinterpret_cast<const bf16x8*>(
            As + (wm * (BM / 2) + mi * 16 + lm) * 128 + ((((uint)ks * 4 + lw) ^ sw) << 4));
#pragma unroll
    for (int ni = 0; ni < 4; ++ni)
#pragma unroll
      for (int ks = 0; ks < 2; ++ks)
        bfr[ni][ks] = *reinterpret_cast<const bf16x8*>(
            Bs + (wn * 64 + ni * 16 + lm) * 128 + ((((uint)ks * 4 + lw) ^ sw) << 4));
#pragma unroll
    for (int ks = 0; ks < 2; ++ks)
#pragma unroll
      for (int mi = 0; mi < MF; ++mi)
#pragma unroll
        for (int ni = 0; ni < 4; ++ni)
          acc[mi][ni] = mfma16<F16>(af[mi][ks], bfr[ni][ks], acc[mi][ni]);
    __syncthreads();
    cur ^= 1;
  }
#pragma unroll
  for (int mi = 0; mi < MF; ++mi)
#pragma unroll
    for (int ni = 0; ni < 4; ++ni) {
      f32x4 a = acc[mi][ni];
      const int row0 = bm + wm * (BM / 2) + mi * 16 + lw * 4;
      const int col  = bn + wn * 64 + ni * 16 + lm;
      if constexpr (BF16OUT) {
        ushort_t* Cb = (ushort_t*)Cv;
#pragma unroll
        for (int r = 0; r < 4; ++r)
          Cb[(size_t)(row0 + r) * N + col] = f2bf(a[r]);
      } else {
        float* Cf = (float*)Cv;
#pragma unroll
        for (int r = 0; r < 4; ++r)
          Cf[(size_t)(row0 + r) * N + col] = a[r];
      }
    }
}

// ---------------- K3: bf16 MFMA block-causal flash attention -----------------
// 64-row q-tile pairs (31-p, p) -> 512 blocks; 8 waves (2 k-split groups of 4);
// 2-buf/group gemm-style 2-phase pipeline; per-wave 2K P; LDS exactly 80K ->
// 2 blocks/CU = 4 waves/SIMD.
__global__ __launch_bounds__(512, 4) void attn_mfma_kernel(
    const ushort_t* __restrict__ qT, const ushort_t* __restrict__ kT,
    const ushort_t* __restrict__ vT, ushort_t* __restrict__ aout) {
  __shared__ __align__(16) char smem[81920];  // 4x16K KV bufs + 8x2K P
  const int tid = threadIdx.x;
  const int l  = tid & 63, w8 = tid >> 6;
  const int grp = w8 >> 2, w4 = w8 & 3;
  const int lm = l & 15, lw = l >> 4, l7 = l & 7, l3 = l >> 3;
  const int bh = blockIdx.y, b = bh >> 4, h = bh & 15;
  const int p = blockIdx.x;                    // 0..15
  const int qbA = 31 - p, qbB = p;             // 64-row q-tile indices
  const int nkbA = ((qbA >> 2) + 1) * 4;       // 20..32
  const int nkbB = ((qbB >> 2) + 1) * 4;       // 4..16 (prefix of A's range)
  const int iters  = nkbA >> 1;                // per-group iterations
  const int bIters = nkbB >> 1;

  bf16x8 qf[2][2];                             // [tile][ks], 16 q-rows per wave
#pragma unroll
  for (int tq = 0; tq < 2; ++tq) {
    const size_t qrow0 = (size_t)bh * SEQ + (tq ? qbB : qbA) * 64 + w4 * 16;
#pragma unroll
    for (int ks = 0; ks < 2; ++ks)
      qf[tq][ks] = *reinterpret_cast<const bf16x8*>(
          qT + (qrow0 + lm) * HD + lw * 8 + ks * 32);
  }

  const char* kTb = reinterpret_cast<const char*>(kT + (size_t)bh * SEQ * HD);
  const char* vTb = reinterpret_cast<const char*>(vT + (size_t)bh * HD * SEQ);
  const uint rloc = (uint)(w4 * 8 + l3);
  const uint csrc = (uint)((l7 ^ l3) << 4);
  char* Pbase = smem + 65536 + w8 * 2048;

  float l_acc[2] = {};
  f32x4 oacc[2][4] = {};

  auto stage = [&](int kb, int bufidx) {
    const char* sK = kTb + ((size_t)(kb * 64) + rloc) * 128 + csrc;
    const char* sV = vTb + (size_t)rloc * (SEQ * 2) + (size_t)kb * 128 + csrc;
    char* dK = smem + (grp * 2 + bufidx) * 16384 + w4 * 1024;
    char* dV = dK + 8192;
    gload16(sK, dK);
    gload16(sK + 4096, dK + 4096);
    gload16(sV, dV);
    gload16(sV + (size_t)32 * SEQ * 2, dV + 4096);
  };

  auto phase = [&](const char* Kb, const char* Vb, const bf16x8 (&qft)[2],
                   float& lat, f32x4 (&oat)[4]) {
    bf16x8 kf[2][4];
#pragma unroll
    for (int ks = 0; ks < 2; ++ks)
#pragma unroll
      for (int g = 0; g < 4; ++g)
        kf[ks][g] = *reinterpret_cast<const bf16x8*>(
            Kb + (g * 16 + lm) * 128 + ((lw * 16 + ks * 64) ^ (l7 << 4)));
    f32x4 st[4] = {};
    __builtin_amdgcn_s_setprio(1);
#pragma unroll
    for (int ks = 0; ks < 2; ++ks)
#pragma unroll
      for (int g = 0; g < 4; ++g)
        st[g] = __builtin_amdgcn_mfma_f32_16x16x32_bf16(kf[ks][g], qft[ks], st[g], 0, 0, 0);
    __builtin_amdgcn_s_setprio(0);
#pragma unroll
    for (int g = 0; g < 4; ++g) {
      f32x4 s4 = st[g];
      float p0 = __builtin_amdgcn_exp2f(s4.x);
      float p1 = __builtin_amdgcn_exp2f(s4.y);
      float p2 = __builtin_amdgcn_exp2f(s4.z);
      float p3 = __builtin_amdgcn_exp2f(s4.w);
      lat += (p0 + p1) + (p2 + p3);
      uint off = (uint)(lm * 128 + ((g * 32 + lw * 8) ^ (l7 << 4)));
      *reinterpret_cast<uint*>(Pbase + off)     = pack_bf16(p0, p1);
      *reinterpret_cast<uint*>(Pbase + off + 4) = pack_bf16(p2, p3);
    }
    bf16x8 vf[2][4];
#pragma unroll
    for (int ks = 0; ks < 2; ++ks)
#pragma unroll
      for (int dn = 0; dn < 4; ++dn)
        vf[ks][dn] = *reinterpret_cast<const bf16x8*>(
            Vb + (dn * 16 + lm) * 128 + ((lw * 16 + ks * 64) ^ (l7 << 4)));
    bf16x8 pf[2];
#pragma unroll
    for (int ks = 0; ks < 2; ++ks)
      pf[ks] = *reinterpret_cast<const bf16x8*>(
          Pbase + lm * 128 + ((lw * 16 + ks * 64) ^ (l7 << 4)));
    __builtin_amdgcn_s_setprio(1);
#pragma unroll
    for (int ks = 0; ks < 2; ++ks)
#pragma unroll
      for (int dn = 0; dn < 4; ++dn)
        oat[dn] = __builtin_amdgcn_mfma_f32_16x16x32_bf16(vf[ks][dn], pf[ks], oat[dn], 0, 0, 0);
    __builtin_amdgcn_s_setprio(0);
  };

  stage(grp, 0);
  __syncthreads();
  int cur = 0;
  for (int i = 0; i < iters; ++i) {
    if (i + 1 < iters) stage(2 * (i + 1) + grp, cur ^ 1);
    const char* Kb = smem + (grp * 2 + cur) * 16384;
    const char* Vb = Kb + 8192;
    phase(Kb, Vb, qf[0], l_acc[0], oacc[0]);
    if (i < bIters) phase(Kb, Vb, qf[1], l_acc[1], oacc[1]);
    __syncthreads();   // drains vmcnt(0): next tile staged; cur readers done
    cur ^= 1;
  }

  // merge group partials: group1 -> LDS (KV region dead), group0 adds.
  if (grp == 1) {
#pragma unroll
    for (int tq = 0; tq < 2; ++tq)
#pragma unroll
      for (int dn = 0; dn < 4; ++dn)
        *reinterpret_cast<f32x4*>(
            smem + (tq * 4 + dn) * 4096 + (w4 * 64 + l) * 16) = oacc[tq][dn];
    float2 lv{l_acc[0], l_acc[1]};
    *reinterpret_cast<float2*>(smem + 32768 + (w4 * 64 + l) * 8) = lv;
  }
  __syncthreads();
  if (grp == 0) {
#pragma unroll
    for (int tq = 0; tq < 2; ++tq)
#pragma unroll
      for (int dn = 0; dn < 4; ++dn)
        oacc[tq][dn] += *reinterpret_cast<const f32x4*>(
            smem + (tq * 4 + dn) * 4096 + (w4 * 64 + l) * 16);
    float2 lv = *reinterpret_cast<const float2*>(smem + 32768 + (w4 * 64 + l) * 8);
    l_acc[0] += lv.x; l_acc[1] += lv.y;

#pragma unroll
    for (int tq = 0; tq < 2; ++tq) {
      const int qb = tq ? qbB : qbA;
      float ls = l_acc[tq];
      ls += __shfl_xor(ls, 16);
      ls += __shfl_xor(ls, 32);
      float inv = 1.f / ls;
      const int qg = qb * 64 + w4 * 16 + lm;
#pragma unroll
      for (int dn = 0; dn < 4; ++dn) {
        f32x4 o = oacc[tq][dn];
        o *= inv;
        size_t off = ((size_t)b * SEQ + qg) * DIM + h * HD + dn * 16 + lw * 4;
        uint2 uo{(uint)f2h(o[0]) | ((uint)f2h(o[1]) << 16),
                 (uint)f2h(o[2]) | ((uint)f2h(o[3]) << 16)};
        *reinterpret_cast<uint2*>(&aout[off]) = uo;
      }
    }
  }
}

// ---------------- launch -----------------------------------------------------
extern "C" void kernel_launch(void* const* d_in, const int* in_sizes, int n_in,
                              void* d_out, int out_size, void* d_ws, size_t ws_size,
                              hipStream_t stream) {
  const float* x       = (const float*)d_in[0];
  const float* Wqkv    = (const float*)d_in[1];
  const float* Wout    = (const float*)d_in[2];
  const float* q_scale = (const float*)d_in[3];
  const float* k_scale = (const float*)d_in[4];
  float* out = (float*)d_out;

  char* ws = (char*)d_ws;
  ushort_t* attn_f16 = (ushort_t*)ws;                      // former qkv region
  size_t off = (size_t)MROW * N3 * 2;
  ushort_t* qT = (ushort_t*)(ws + off); off += (size_t)NB * NH * SEQ * HD * 2;
  ushort_t* kT = (ushort_t*)(ws + off); off += (size_t)NB * NH * SEQ * HD * 2;
  ushort_t* vT = (ushort_t*)(ws + off); off += (size_t)NB * NH * SEQ * HD * 2;
  float* tab   = (float*)(ws + off);    off += (size_t)SEQ * 64 * 4;
  ushort_t* xh   = (ushort_t*)(ws + off); off += (size_t)MROW * DIM * 2;
  ushort_t* wqh  = (ushort_t*)(ws + off); off += (size_t)N3 * DIM * 2;
  ushort_t* wo16 = (ushort_t*)(ws + off);

  prep_kernel<<<dim3(MROW * DIM / 4 / 256), dim3(256), 0, stream>>>(
      x, Wqkv, Wout, xh, wqh, wo16, tab);
  gemm_qkv_kernel<<<dim3(N3 / 128, MROW / 128), dim3(256), 0, stream>>>(
      xh, wqh, q_scale, k_scale, tab, qT, kT, vT);
  attn_mfma_kernel<<<dim3(16, NB * NH), dim3(512), 0, stream>>>(qT, kT, vT, attn_f16);
  gemm_mfma_kernel<128, false, true><<<dim3(DIM / 128, MROW / 128), dim3(256), 0, stream>>>(
      attn_f16, wo16, out, DIM, DIM);
}